// Round 1
// baseline (943.385 us; speedup 1.0000x reference)
//
#include <hip/hip_runtime.h>
#include <stdint.h>

typedef short bf16x8 __attribute__((ext_vector_type(8)));
typedef float f32x4 __attribute__((ext_vector_type(4)));
typedef unsigned short u16x4 __attribute__((ext_vector_type(4)));
typedef unsigned short u16x8 __attribute__((ext_vector_type(8)));

constexpr int NB = 8, NS = 1024, ND = 1024, NH = 16, NHD = 64;

static __device__ __forceinline__ unsigned short f2bf(float f) {
    union { float f; uint32_t u; } v; v.f = f;
    uint32_t r = (v.u + 0x7fffu + ((v.u >> 16) & 1u)) >> 16;
    return (unsigned short)r;
}

// mask accessor: ms==4 -> 4-byte elements (int32 0/1 OR f32 0.0/1.0, both "nonzero" test)
//                ms==1 -> 1-byte elements (bool)
static __device__ __forceinline__ bool mask_at(const void* m, size_t idx, int ms) {
    if (ms == 4) return ((const unsigned int*)m)[idx] != 0u;
    return ((const unsigned char*)m)[idx] != 0;
}

__global__ void detect_mask(const unsigned int* __restrict__ m, int* __restrict__ flag) {
    int l = threadIdx.x;
    bool bad = false;
    for (int i = l; i < 1024; i += 64) {
        unsigned int w = m[i];
        // int32 mask words are 0/1; f32 mask words are 0 or 0x3f800000.
        // packed-byte (bool) data will show other word values.
        bad |= (w > 1u && w != 0x3f800000u);
    }
    bad = (bool)__any(bad);
    if (l == 0) *flag = bad ? 1 : 4;
}

__global__ __launch_bounds__(256) void cvt_kernel(const float* __restrict__ in,
                                                  u16x8* __restrict__ out, int n8) {
    int stride = gridDim.x * blockDim.x;
    for (int idx = blockIdx.x * blockDim.x + threadIdx.x; idx < n8; idx += stride) {
        const float4* p = (const float4*)in + 2 * (size_t)idx;
        float4 a = p[0], b = p[1];
        u16x8 o;
        o[0] = f2bf(a.x); o[1] = f2bf(a.y); o[2] = f2bf(a.z); o[3] = f2bf(a.w);
        o[4] = f2bf(b.x); o[5] = f2bf(b.y); o[6] = f2bf(b.z); o[7] = f2bf(b.w);
        out[idx] = o;
    }
}

// C(M x N) = A(M x K, row-major bf16) * Bw(N x K, row-major bf16)^T + bias
// M = NB*NS = 8192, N = 1024, K = 1024.
// mode 0: write C as bf16 row-major (b,s,d).  mode 1: write transposed Vt[b,h,d,s] bf16.
__global__ __launch_bounds__(256) void proj_gemm(const unsigned short* __restrict__ A,
                                                 const unsigned short* __restrict__ Bw,
                                                 const float* __restrict__ bias,
                                                 unsigned short* __restrict__ C, int mode) {
    int l = threadIdx.x & 63, w = threadIdx.x >> 6;
    int lr = l & 15, lg = l >> 4;
    int m_base = blockIdx.x * 128 + (w >> 1) * 64;
    int n_base = blockIdx.y * 128 + (w & 1) * 64;
    f32x4 acc[4][4] = {};
    for (int k = 0; k < 1024; k += 32) {
        bf16x8 af[4], bfr[4];
        #pragma unroll
        for (int mt = 0; mt < 4; mt++)
            af[mt] = *(const bf16x8*)(A + (size_t)(m_base + mt * 16 + lr) * 1024 + k + lg * 8);
        #pragma unroll
        for (int nt = 0; nt < 4; nt++)
            bfr[nt] = *(const bf16x8*)(Bw + (size_t)(n_base + nt * 16 + lr) * 1024 + k + lg * 8);
        #pragma unroll
        for (int mt = 0; mt < 4; mt++) {
            #pragma unroll
            for (int nt = 0; nt < 4; nt++)
                acc[mt][nt] = __builtin_amdgcn_mfma_f32_16x16x32_bf16(af[mt], bfr[nt], acc[mt][nt], 0, 0, 0);
        }
    }
    #pragma unroll
    for (int mt = 0; mt < 4; mt++) {
        #pragma unroll
        for (int nt = 0; nt < 4; nt++) {
            int col = n_base + nt * 16 + lr;        // output feature (n)
            int row0 = m_base + mt * 16 + lg * 4;   // flattened (b*S + s)
            float bv = bias[col];
            if (mode == 0) {
                #pragma unroll
                for (int r = 0; r < 4; r++)
                    C[(size_t)(row0 + r) * 1024 + col] = f2bf(acc[mt][nt][r] + bv);
            } else {
                int bb = row0 >> 10, s0 = row0 & 1023;
                int hh = col >> 6, dd = col & 63;
                u16x4 pk;
                #pragma unroll
                for (int r = 0; r < 4; r++) pk[r] = f2bf(acc[mt][nt][r] + bv);
                *(u16x4*)(C + ((size_t)((bb * NH + hh) * NHD + dd)) * NS + s0) = pk;
            }
        }
    }
}

// TR[b,q,k] = (1-l1)*l2 * time_attn + l1 * rel_attn   (per-(b,q,k), shared by all heads)
__global__ __launch_bounds__(256) void tr_kernel(const float* __restrict__ rel,
                                                 const float* __restrict__ ts,
                                                 const void* __restrict__ maskp,
                                                 const int* __restrict__ msflag,
                                                 const float* __restrict__ l1p,
                                                 const float* __restrict__ l2p,
                                                 float* __restrict__ TR) {
    __shared__ float s_tm[4], s_rm[4], s_ts[4], s_rs[4];
    int row = blockIdx.x;               // b*S + q
    int t = threadIdx.x, w = t >> 6, l = t & 63;
    int ms = *msflag;
    size_t base = (size_t)row * NS;
    float4 r4 = ((const float4*)(rel + base))[t];
    float4 t4 = ((const float4*)(ts + base))[t];
    float rr[4], tt[4];
    *(float4*)rr = r4; *(float4*)tt = t4;
    float tv[4], rv[4];
    float tmx = -3.0e38f, rmx = -3.0e38f;
    #pragma unroll
    for (int j = 0; j < 4; j++) {
        bool m = mask_at(maskp, base + t * 4 + j, ms);
        // time: where(m, -1e5, exp(-|ts|))
        tv[j] = m ? -100000.0f : __expf(-fabsf(tt[j]));
        // rel: rel_m = rel * mf;  where(rel_m==0, -1e5, rel_m)
        float rm_ = m ? rr[j] : 0.0f;
        rv[j] = (rm_ == 0.0f) ? -100000.0f : rm_;
        tmx = fmaxf(tmx, tv[j]); rmx = fmaxf(rmx, rv[j]);
    }
    #pragma unroll
    for (int off = 1; off < 64; off <<= 1) {
        tmx = fmaxf(tmx, __shfl_xor(tmx, off));
        rmx = fmaxf(rmx, __shfl_xor(rmx, off));
    }
    if (l == 0) { s_tm[w] = tmx; s_rm[w] = rmx; }
    __syncthreads();
    tmx = fmaxf(fmaxf(s_tm[0], s_tm[1]), fmaxf(s_tm[2], s_tm[3]));
    rmx = fmaxf(fmaxf(s_rm[0], s_rm[1]), fmaxf(s_rm[2], s_rm[3]));
    float te[4], re[4], tsum = 0.f, rsum = 0.f;
    #pragma unroll
    for (int j = 0; j < 4; j++) {
        te[j] = __expf(tv[j] - tmx); tsum += te[j];
        re[j] = __expf(rv[j] - rmx); rsum += re[j];
    }
    #pragma unroll
    for (int off = 1; off < 64; off <<= 1) {
        tsum += __shfl_xor(tsum, off);
        rsum += __shfl_xor(rsum, off);
    }
    if (l == 0) { s_ts[w] = tsum; s_rs[w] = rsum; }
    __syncthreads();
    tsum = s_ts[0] + s_ts[1] + s_ts[2] + s_ts[3];
    rsum = s_rs[0] + s_rs[1] + s_rs[2] + s_rs[3];
    float l1 = *l1p, l2 = *l2p;
    float ti = ((1.0f - l1) * l2) / tsum;
    float ri = l1 / rsum;
    float4 o;
    o.x = te[0] * ti + re[0] * ri;
    o.y = te[1] * ti + re[1] * ri;
    o.z = te[2] * ti + re[2] * ri;
    o.w = te[3] * ti + re[3] * ri;
    ((float4*)(TR + base))[t] = o;
}

// Per block: (b, h, 16 q-rows). Wave w owns k in [w*256, w*256+256).
// scores via MFMA -> masked softmax over full row -> prob_total = cp*prob + TR -> store f32.
__global__ __launch_bounds__(256) void att_kernel(const unsigned short* __restrict__ Qb,
                                                  const unsigned short* __restrict__ Kb,
                                                  const void* __restrict__ maskp,
                                                  const int* __restrict__ msflag,
                                                  const float* __restrict__ TR,
                                                  const float* __restrict__ l1p,
                                                  const float* __restrict__ l2p,
                                                  float* __restrict__ probOut) {
    __shared__ float red[4][16];
    int bid = blockIdx.x;
    int qt = bid & 63;
    int h = (bid >> 6) & 15;
    int b = bid >> 10;
    int tid = threadIdx.x, w = tid >> 6, l = tid & 63, lr = l & 15, lg = l >> 4;
    int q0 = qt * 16;
    int ms = *msflag;

    const unsigned short* qp = Qb + ((size_t)b * NS + q0 + lr) * ND + h * NHD + lg * 8;
    bf16x8 aq0 = *(const bf16x8*)qp;
    bf16x8 aq1 = *(const bf16x8*)(qp + 32);

    f32x4 acc[16] = {};
    #pragma unroll
    for (int t = 0; t < 16; t++) {
        int k0 = w * 256 + t * 16;
        const unsigned short* kp = Kb + ((size_t)b * NS + k0 + lr) * ND + h * NHD + lg * 8;
        bf16x8 b0 = *(const bf16x8*)kp;
        bf16x8 b1 = *(const bf16x8*)(kp + 32);
        acc[t] = __builtin_amdgcn_mfma_f32_16x16x32_bf16(aq0, b0, acc[t], 0, 0, 0);
        acc[t] = __builtin_amdgcn_mfma_f32_16x16x32_bf16(aq1, b1, acc[t], 0, 0, 0);
    }
    // scale + mask
    #pragma unroll
    for (int t = 0; t < 16; t++) {
        int kcol = w * 256 + t * 16 + lr;
        #pragma unroll
        for (int r = 0; r < 4; r++) {
            int q = q0 + lg * 4 + r;
            bool m = mask_at(maskp, ((size_t)b * NS + q) * NS + kcol, ms);
            acc[t][r] = m ? -1.0e32f : acc[t][r] * 0.125f;
        }
    }
    // row max (rows live in lanes sharing lg; reduce over lr then across waves)
    float mx[4];
    #pragma unroll
    for (int r = 0; r < 4; r++) {
        float m_ = acc[0][r];
        #pragma unroll
        for (int t = 1; t < 16; t++) m_ = fmaxf(m_, acc[t][r]);
        #pragma unroll
        for (int off = 1; off < 16; off <<= 1) m_ = fmaxf(m_, __shfl_xor(m_, off));
        mx[r] = m_;
    }
    if (lr == 0) {
        #pragma unroll
        for (int r = 0; r < 4; r++) red[w][lg * 4 + r] = mx[r];
    }
    __syncthreads();
    float rowmax[4];
    #pragma unroll
    for (int r = 0; r < 4; r++) {
        int q = lg * 4 + r;
        rowmax[r] = fmaxf(fmaxf(red[0][q], red[1][q]), fmaxf(red[2][q], red[3][q]));
    }
    __syncthreads();
    // exp + row sum
    float sm[4] = {0.f, 0.f, 0.f, 0.f};
    #pragma unroll
    for (int t = 0; t < 16; t++) {
        #pragma unroll
        for (int r = 0; r < 4; r++) {
            float e = __expf(acc[t][r] - rowmax[r]);
            acc[t][r] = e;
            sm[r] += e;
        }
    }
    #pragma unroll
    for (int r = 0; r < 4; r++) {
        #pragma unroll
        for (int off = 1; off < 16; off <<= 1) sm[r] += __shfl_xor(sm[r], off);
    }
    if (lr == 0) {
        #pragma unroll
        for (int r = 0; r < 4; r++) red[w][lg * 4 + r] = sm[r];
    }
    __syncthreads();
    float rinv[4];
    float l1 = *l1p, l2 = *l2p;
    float cp = (1.0f - l1) * (1.0f - l2);
    #pragma unroll
    for (int r = 0; r < 4; r++) {
        int q = lg * 4 + r;
        rinv[r] = cp / (red[0][q] + red[1][q] + red[2][q] + red[3][q]);
    }
    float* po = probOut + ((size_t)(b * NH + h)) * NS * NS;
    #pragma unroll
    for (int t = 0; t < 16; t++) {
        int kcol = w * 256 + t * 16 + lr;
        #pragma unroll
        for (int r = 0; r < 4; r++) {
            int q = q0 + lg * 4 + r;
            float p = acc[t][r] * rinv[r] + TR[((size_t)b * NS + q) * NS + kcol];
            po[(size_t)q * NS + kcol] = p;
        }
    }
}

// out[b, s, h*64+d] = sum_k prob[b,h,s,k] * V[b,k,h*64+d]; A = prob (f32->bf16), B = Vt (d,k) bf16
__global__ __launch_bounds__(256) void pv_kernel(const float* __restrict__ prob,
                                                 const unsigned short* __restrict__ Vt,
                                                 float* __restrict__ outp) {
    int bid = blockIdx.x;
    int mt = bid & 15;
    int h = (bid >> 4) & 15;
    int b = bid >> 8;
    int tid = threadIdx.x, w = tid >> 6, l = tid & 63, lr = l & 15, lg = l >> 4;
    int q0 = mt * 64 + w * 16;
    const float* prow = prob + ((size_t)(b * NH + h)) * NS * NS;
    const unsigned short* vt = Vt + ((size_t)(b * NH + h)) * NHD * NS;
    f32x4 acc[4] = {};
    for (int k = 0; k < 1024; k += 32) {
        const float* ap = prow + (size_t)(q0 + lr) * NS + k + lg * 8;
        float4 a0 = *(const float4*)ap;
        float4 a1 = *(const float4*)(ap + 4);
        bf16x8 af;
        af[0] = (short)f2bf(a0.x); af[1] = (short)f2bf(a0.y);
        af[2] = (short)f2bf(a0.z); af[3] = (short)f2bf(a0.w);
        af[4] = (short)f2bf(a1.x); af[5] = (short)f2bf(a1.y);
        af[6] = (short)f2bf(a1.z); af[7] = (short)f2bf(a1.w);
        #pragma unroll
        for (int nt = 0; nt < 4; nt++) {
            bf16x8 bv = *(const bf16x8*)(vt + (size_t)(nt * 16 + lr) * NS + k + lg * 8);
            acc[nt] = __builtin_amdgcn_mfma_f32_16x16x32_bf16(af, bv, acc[nt], 0, 0, 0);
        }
    }
    #pragma unroll
    for (int nt = 0; nt < 4; nt++) {
        #pragma unroll
        for (int r = 0; r < 4; r++) {
            int s = q0 + lg * 4 + r;
            int d = nt * 16 + lr;
            outp[((size_t)b * NS + s) * ND + h * NHD + d] = acc[nt][r];
        }
    }
}

extern "C" void kernel_launch(void* const* d_in, const int* in_sizes, int n_in,
                              void* d_out, int out_size, void* d_ws, size_t ws_size,
                              hipStream_t stream) {
    const float* query = (const float*)d_in[0];
    const float* key   = (const float*)d_in[1];
    const float* value = (const float*)d_in[2];
    const float* rel   = (const float*)d_in[3];
    const float* ts    = (const float*)d_in[4];
    const void*  mask  = d_in[5];
    const float* l1p   = (const float*)d_in[6];
    const float* l2p   = (const float*)d_in[7];
    // d_in[8] = encode_pos (unused by reference)
    const float* Wq = (const float*)d_in[9];
    const float* bq = (const float*)d_in[10];
    const float* Wk = (const float*)d_in[11];
    const float* bk = (const float*)d_in[12];
    const float* Wv = (const float*)d_in[13];
    const float* bv = (const float*)d_in[14];

    char* ws = (char*)d_ws;
    const size_t SZ = (size_t)NB * NS * ND * 2;   // 16.78 MB (one bf16 (B,S,D) tensor)
    unsigned short* Qbf = (unsigned short*)(ws);
    unsigned short* Kbf = (unsigned short*)(ws + SZ);
    unsigned short* Vt  = (unsigned short*)(ws + 2 * SZ);
    unsigned short* Xq  = (unsigned short*)(ws + 3 * SZ);
    unsigned short* Xk  = (unsigned short*)(ws + 4 * SZ);
    unsigned short* Xv  = (unsigned short*)(ws + 5 * SZ);
    unsigned short* Wqb = (unsigned short*)(ws + 6 * SZ);
    unsigned short* Wkb = (unsigned short*)(ws + 6 * SZ + 2u * 1024 * 1024);
    unsigned short* Wvb = (unsigned short*)(ws + 6 * SZ + 4u * 1024 * 1024);
    int* msflag         = (int*)(ws + 6 * SZ + 6u * 1024 * 1024);
    // TR (33.5 MB f32) reuses the Xq/Xk region — written only AFTER projections finish.
    float* TR = (float*)(ws + 3 * SZ);

    detect_mask<<<1, 64, 0, stream>>>((const unsigned int*)mask, msflag);

    const int nX8 = NB * NS * ND / 8;     // 1048576
    const int nW8 = 1024 * 1024 / 8;      // 131072
    cvt_kernel<<<1024, 256, 0, stream>>>(query, (u16x8*)Xq, nX8);
    cvt_kernel<<<1024, 256, 0, stream>>>(key,   (u16x8*)Xk, nX8);
    cvt_kernel<<<1024, 256, 0, stream>>>(value, (u16x8*)Xv, nX8);
    cvt_kernel<<<256, 256, 0, stream>>>(Wq, (u16x8*)Wqb, nW8);
    cvt_kernel<<<256, 256, 0, stream>>>(Wk, (u16x8*)Wkb, nW8);
    cvt_kernel<<<256, 256, 0, stream>>>(Wv, (u16x8*)Wvb, nW8);

    dim3 pg(64, 8);
    proj_gemm<<<pg, 256, 0, stream>>>(Xq, Wqb, bq, Qbf, 0);
    proj_gemm<<<pg, 256, 0, stream>>>(Xk, Wkb, bk, Kbf, 0);
    proj_gemm<<<pg, 256, 0, stream>>>(Xv, Wvb, bv, Vt, 1);

    tr_kernel<<<NB * NS, 256, 0, stream>>>(rel, ts, mask, msflag, l1p, l2p, TR);

    float* outp = (float*)d_out;
    float* probOut = outp + (size_t)NB * NS * ND;
    att_kernel<<<NB * NH * (NS / 16), 256, 0, stream>>>(Qbf, Kbf, mask, msflag, TR, l1p, l2p, probOut);
    pv_kernel<<<NB * NH * (NS / 64), 256, 0, stream>>>(probOut, Vt, outp);
}

// Round 2
// 781.283 us; speedup vs baseline: 1.2075x; 1.2075x over previous
//
#include <hip/hip_runtime.h>
#include <stdint.h>

typedef short bf16x8 __attribute__((ext_vector_type(8)));
typedef float f32x4 __attribute__((ext_vector_type(4)));
typedef unsigned short u16x4 __attribute__((ext_vector_type(4)));
typedef unsigned short u16x8 __attribute__((ext_vector_type(8)));

constexpr int NB = 8, NS = 1024, ND = 1024, NH = 16, NHD = 64;

static __device__ __forceinline__ unsigned short f2bf(float f) {
    union { float f; uint32_t u; } v; v.f = f;
    uint32_t r = (v.u + 0x7fffu + ((v.u >> 16) & 1u)) >> 16;
    return (unsigned short)r;
}

// mask accessor: ms==4 -> 4-byte elements (int32 0/1 OR f32 0.0/1.0)
//                ms==1 -> 1-byte elements (bool)
static __device__ __forceinline__ bool mask_at(const void* m, size_t idx, int ms) {
    if (ms == 4) return ((const unsigned int*)m)[idx] != 0u;
    return ((const unsigned char*)m)[idx] != 0;
}

__global__ void detect_mask(const unsigned int* __restrict__ m, int* __restrict__ flag) {
    int l = threadIdx.x;
    bool bad = false;
    for (int i = l; i < 1024; i += 64) {
        unsigned int w = m[i];
        bad |= (w > 1u && w != 0x3f800000u);
    }
    bad = (bool)__any(bad);
    if (l == 0) *flag = bad ? 1 : 4;
}

__global__ __launch_bounds__(256) void cvt_kernel(const float* __restrict__ in,
                                                  u16x8* __restrict__ out, int n8) {
    int stride = gridDim.x * blockDim.x;
    for (int idx = blockIdx.x * blockDim.x + threadIdx.x; idx < n8; idx += stride) {
        const float4* p = (const float4*)in + 2 * (size_t)idx;
        float4 a = p[0], b = p[1];
        u16x8 o;
        o[0] = f2bf(a.x); o[1] = f2bf(a.y); o[2] = f2bf(a.z); o[3] = f2bf(a.w);
        o[4] = f2bf(b.x); o[5] = f2bf(b.y); o[6] = f2bf(b.z); o[7] = f2bf(b.w);
        out[idx] = o;
    }
}

// C(M x N) = A(M x K, row-major bf16) * Bw(N x K, row-major bf16)^T + bias
// mode 0: write C bf16 row-major (b,s,d).  mode 1: write transposed Vt[b,h,d,s] bf16.
__global__ __launch_bounds__(256) void proj_gemm(const unsigned short* __restrict__ A,
                                                 const unsigned short* __restrict__ Bw,
                                                 const float* __restrict__ bias,
                                                 unsigned short* __restrict__ C, int mode) {
    int l = threadIdx.x & 63, w = threadIdx.x >> 6;
    int lr = l & 15, lg = l >> 4;
    int m_base = blockIdx.x * 128 + (w >> 1) * 64;
    int n_base = blockIdx.y * 128 + (w & 1) * 64;
    f32x4 acc[4][4] = {};
    for (int k = 0; k < 1024; k += 32) {
        bf16x8 af[4], bfr[4];
        #pragma unroll
        for (int mt = 0; mt < 4; mt++)
            af[mt] = *(const bf16x8*)(A + (size_t)(m_base + mt * 16 + lr) * 1024 + k + lg * 8);
        #pragma unroll
        for (int nt = 0; nt < 4; nt++)
            bfr[nt] = *(const bf16x8*)(Bw + (size_t)(n_base + nt * 16 + lr) * 1024 + k + lg * 8);
        #pragma unroll
        for (int mt = 0; mt < 4; mt++) {
            #pragma unroll
            for (int nt = 0; nt < 4; nt++)
                acc[mt][nt] = __builtin_amdgcn_mfma_f32_16x16x32_bf16(af[mt], bfr[nt], acc[mt][nt], 0, 0, 0);
        }
    }
    #pragma unroll
    for (int mt = 0; mt < 4; mt++) {
        #pragma unroll
        for (int nt = 0; nt < 4; nt++) {
            int col = n_base + nt * 16 + lr;
            int row0 = m_base + mt * 16 + lg * 4;
            float bv = bias[col];
            if (mode == 0) {
                #pragma unroll
                for (int r = 0; r < 4; r++)
                    C[(size_t)(row0 + r) * 1024 + col] = f2bf(acc[mt][nt][r] + bv);
            } else {
                int bb = row0 >> 10, s0 = row0 & 1023;
                int hh = col >> 6, dd = col & 63;
                u16x4 pk;
                #pragma unroll
                for (int r = 0; r < 4; r++) pk[r] = f2bf(acc[mt][nt][r] + bv);
                *(u16x4*)(C + ((size_t)((bb * NH + hh) * NHD + dd)) * NS + s0) = pk;
            }
        }
    }
}

// TR[b,q,k] = (1-l1)*l2 * time_attn + l1 * rel_attn  (shared by all heads)
// Also emits PM[b,q][k/32] packed mask bits (bit=1 -> masked/excluded in scores).
__global__ __launch_bounds__(256) void tr_kernel(const float* __restrict__ rel,
                                                 const float* __restrict__ ts,
                                                 const void* __restrict__ maskp,
                                                 const int* __restrict__ msflag,
                                                 const float* __restrict__ l1p,
                                                 const float* __restrict__ l2p,
                                                 float* __restrict__ TR,
                                                 uint32_t* __restrict__ PM) {
    __shared__ float s_tm[4], s_rm[4], s_ts[4], s_rs[4];
    __shared__ unsigned char s_nib[256];
    int row = blockIdx.x;               // b*S + q
    int t = threadIdx.x, w = t >> 6, l = t & 63;
    int ms = *msflag;
    size_t base = (size_t)row * NS;
    float4 r4 = ((const float4*)(rel + base))[t];
    float4 t4 = ((const float4*)(ts + base))[t];
    float rr[4], tt[4];
    *(float4*)rr = r4; *(float4*)tt = t4;
    float tv[4], rv[4];
    unsigned nib = 0;
    float tmx = -3.0e38f, rmx = -3.0e38f;
    #pragma unroll
    for (int j = 0; j < 4; j++) {
        bool m = mask_at(maskp, base + t * 4 + j, ms);
        nib |= (m ? 1u : 0u) << j;
        tv[j] = m ? -100000.0f : __expf(-fabsf(tt[j]));
        float rm_ = m ? rr[j] : 0.0f;
        rv[j] = (rm_ == 0.0f) ? -100000.0f : rm_;
        tmx = fmaxf(tmx, tv[j]); rmx = fmaxf(rmx, rv[j]);
    }
    s_nib[t] = (unsigned char)nib;
    #pragma unroll
    for (int off = 1; off < 64; off <<= 1) {
        tmx = fmaxf(tmx, __shfl_xor(tmx, off));
        rmx = fmaxf(rmx, __shfl_xor(rmx, off));
    }
    if (l == 0) { s_tm[w] = tmx; s_rm[w] = rmx; }
    __syncthreads();
    tmx = fmaxf(fmaxf(s_tm[0], s_tm[1]), fmaxf(s_tm[2], s_tm[3]));
    rmx = fmaxf(fmaxf(s_rm[0], s_rm[1]), fmaxf(s_rm[2], s_rm[3]));
    float te[4], re[4], tsum = 0.f, rsum = 0.f;
    #pragma unroll
    for (int j = 0; j < 4; j++) {
        te[j] = __expf(tv[j] - tmx); tsum += te[j];
        re[j] = __expf(rv[j] - rmx); rsum += re[j];
    }
    #pragma unroll
    for (int off = 1; off < 64; off <<= 1) {
        tsum += __shfl_xor(tsum, off);
        rsum += __shfl_xor(rsum, off);
    }
    if (l == 0) { s_ts[w] = tsum; s_rs[w] = rsum; }
    __syncthreads();
    tsum = s_ts[0] + s_ts[1] + s_ts[2] + s_ts[3];
    rsum = s_rs[0] + s_rs[1] + s_rs[2] + s_rs[3];
    float l1 = *l1p, l2 = *l2p;
    float ti = ((1.0f - l1) * l2) / tsum;
    float ri = l1 / rsum;
    float4 o;
    o.x = te[0] * ti + re[0] * ri;
    o.y = te[1] * ti + re[1] * ri;
    o.z = te[2] * ti + re[2] * ri;
    o.w = te[3] * ti + re[3] * ri;
    ((float4*)(TR + base))[t] = o;
    // pack mask bits: word w32 covers k in [w32*32, w32*32+32)
    if (t < 32) {
        uint32_t word = 0;
        #pragma unroll
        for (int i = 0; i < 8; i++)
            word |= ((uint32_t)s_nib[t * 8 + i]) << (i * 4);
        PM[(size_t)row * 32 + t] = word;
    }
}

// Swapped-operand scores: D rows = k (lg*4+reg), cols = q (lr).
// Each lane owns ONE q-row (q = q0+lr) with k in contiguous 4-chunks -> float4 TR/prob I/O.
__global__ __launch_bounds__(256) void att_kernel(const unsigned short* __restrict__ Qb,
                                                  const unsigned short* __restrict__ Kb,
                                                  const uint32_t* __restrict__ PM,
                                                  const float* __restrict__ TR,
                                                  const float* __restrict__ l1p,
                                                  const float* __restrict__ l2p,
                                                  float* __restrict__ probOut) {
    __shared__ float redm[4][16];
    __shared__ float reds[4][16];
    int bid = blockIdx.x;
    int qt = bid & 63;
    int h = (bid >> 6) & 15;
    int b = bid >> 10;
    int tid = threadIdx.x, w = tid >> 6, l = tid & 63, lr = l & 15, lg = l >> 4;
    int q0 = qt * 16;
    int k_base = w * 256;
    int q = q0 + lr;                      // this lane's q-row
    size_t browq = (size_t)b * NS + q;

    // Q fragment (B operand): rows = q0+lr
    const unsigned short* qp = Qb + ((size_t)b * NS + q0 + lr) * ND + h * NHD + lg * 8;
    bf16x8 bq0 = *(const bf16x8*)qp;
    bf16x8 bq1 = *(const bf16x8*)(qp + 32);

    // packed mask words for this lane's q-row, k range [k_base, k_base+256)
    uint32_t pm[8];
    const uint32_t* pmrow = PM + browq * 32 + (k_base >> 5);
    #pragma unroll
    for (int j = 0; j < 8; j++) pm[j] = pmrow[j];

    f32x4 acc[16] = {};
    #pragma unroll
    for (int t = 0; t < 16; t++) {
        int k0 = k_base + t * 16;
        const unsigned short* kp = Kb + ((size_t)b * NS + k0 + lr) * ND + h * NHD + lg * 8;
        bf16x8 a0 = *(const bf16x8*)kp;
        bf16x8 a1 = *(const bf16x8*)(kp + 32);
        acc[t] = __builtin_amdgcn_mfma_f32_16x16x32_bf16(a0, bq0, acc[t], 0, 0, 0);
        acc[t] = __builtin_amdgcn_mfma_f32_16x16x32_bf16(a1, bq1, acc[t], 0, 0, 0);
    }
    // scale + mask (bit 1 -> masked -> -1e32)
    #pragma unroll
    for (int t = 0; t < 16; t++) {
        uint32_t word = pm[t >> 1];
        int shift = (t & 1) * 16 + lg * 4;
        #pragma unroll
        for (int r = 0; r < 4; r++) {
            bool m = (word >> (shift + r)) & 1u;
            acc[t][r] = m ? -1.0e32f : acc[t][r] * 0.125f;
        }
    }
    // row max: serial over own 64 vals, then across lg groups (xor 16,32), then across waves
    float mx = acc[0][0];
    #pragma unroll
    for (int t = 0; t < 16; t++) {
        #pragma unroll
        for (int r = 0; r < 4; r++) mx = fmaxf(mx, acc[t][r]);
    }
    mx = fmaxf(mx, __shfl_xor(mx, 16));
    mx = fmaxf(mx, __shfl_xor(mx, 32));
    if (l < 16) redm[w][l] = mx;
    __syncthreads();
    float rowmax = fmaxf(fmaxf(redm[0][lr], redm[1][lr]), fmaxf(redm[2][lr], redm[3][lr]));
    // exp + row sum
    float sm = 0.f;
    #pragma unroll
    for (int t = 0; t < 16; t++) {
        #pragma unroll
        for (int r = 0; r < 4; r++) {
            float e = __expf(acc[t][r] - rowmax);
            acc[t][r] = e;
            sm += e;
        }
    }
    sm += __shfl_xor(sm, 16);
    sm += __shfl_xor(sm, 32);
    if (l < 16) reds[w][l] = sm;
    __syncthreads();
    float total = reds[0][lr] + reds[1][lr] + reds[2][lr] + reds[3][lr];
    float l1 = *l1p, l2 = *l2p;
    float rinv = ((1.0f - l1) * (1.0f - l2)) / total;
    // final: p = prob*cp + TR, streamed float4
    float* po = probOut + ((size_t)(b * NH + h)) * NS * NS + (size_t)q * NS;
    const float* trrow = TR + browq * NS;
    #pragma unroll
    for (int t = 0; t < 16; t++) {
        int kc = k_base + t * 16 + lg * 4;
        float4 tr4 = *(const float4*)(trrow + kc);
        float4 o;
        o.x = acc[t][0] * rinv + tr4.x;
        o.y = acc[t][1] * rinv + tr4.y;
        o.z = acc[t][2] * rinv + tr4.z;
        o.w = acc[t][3] * rinv + tr4.w;
        *(float4*)(po + kc) = o;
    }
}

// out[b,s,h*64+d] = sum_k prob[b,h,s,k] * V[b,k,h*64+d]; A = prob (f32->bf16), B = Vt (d,k) bf16
__global__ __launch_bounds__(256) void pv_kernel(const float* __restrict__ prob,
                                                 const unsigned short* __restrict__ Vt,
                                                 float* __restrict__ outp) {
    int bid = blockIdx.x;
    int mt = bid & 15;
    int h = (bid >> 4) & 15;
    int b = bid >> 8;
    int tid = threadIdx.x, w = tid >> 6, l = tid & 63, lr = l & 15, lg = l >> 4;
    int q0 = mt * 64 + w * 16;
    const float* prow = prob + ((size_t)(b * NH + h)) * NS * NS;
    const unsigned short* vt = Vt + ((size_t)(b * NH + h)) * NHD * NS;
    f32x4 acc[4] = {};
    for (int k = 0; k < 1024; k += 32) {
        const float* ap = prow + (size_t)(q0 + lr) * NS + k + lg * 8;
        float4 a0 = *(const float4*)ap;
        float4 a1 = *(const float4*)(ap + 4);
        bf16x8 af;
        af[0] = (short)f2bf(a0.x); af[1] = (short)f2bf(a0.y);
        af[2] = (short)f2bf(a0.z); af[3] = (short)f2bf(a0.w);
        af[4] = (short)f2bf(a1.x); af[5] = (short)f2bf(a1.y);
        af[6] = (short)f2bf(a1.z); af[7] = (short)f2bf(a1.w);
        #pragma unroll
        for (int nt = 0; nt < 4; nt++) {
            bf16x8 bv = *(const bf16x8*)(vt + (size_t)(nt * 16 + lr) * NS + k + lg * 8);
            acc[nt] = __builtin_amdgcn_mfma_f32_16x16x32_bf16(af, bv, acc[nt], 0, 0, 0);
        }
    }
    #pragma unroll
    for (int nt = 0; nt < 4; nt++) {
        #pragma unroll
        for (int r = 0; r < 4; r++) {
            int s = q0 + lg * 4 + r;
            int d = nt * 16 + lr;
            outp[((size_t)b * NS + s) * ND + h * NHD + d] = acc[nt][r];
        }
    }
}

extern "C" void kernel_launch(void* const* d_in, const int* in_sizes, int n_in,
                              void* d_out, int out_size, void* d_ws, size_t ws_size,
                              hipStream_t stream) {
    const float* query = (const float*)d_in[0];
    const float* key   = (const float*)d_in[1];
    const float* value = (const float*)d_in[2];
    const float* rel   = (const float*)d_in[3];
    const float* ts    = (const float*)d_in[4];
    const void*  mask  = d_in[5];
    const float* l1p   = (const float*)d_in[6];
    const float* l2p   = (const float*)d_in[7];
    const float* Wq = (const float*)d_in[9];
    const float* bq = (const float*)d_in[10];
    const float* Wk = (const float*)d_in[11];
    const float* bk = (const float*)d_in[12];
    const float* Wv = (const float*)d_in[13];
    const float* bv = (const float*)d_in[14];

    char* ws = (char*)d_ws;
    const size_t SZ = (size_t)NB * NS * ND * 2;   // 16.78 MB
    unsigned short* Qbf = (unsigned short*)(ws);
    unsigned short* Kbf = (unsigned short*)(ws + SZ);
    unsigned short* Vt  = (unsigned short*)(ws + 2 * SZ);
    unsigned short* Xq  = (unsigned short*)(ws + 3 * SZ);
    unsigned short* Xk  = (unsigned short*)(ws + 4 * SZ);
    unsigned short* Xv  = (unsigned short*)(ws + 5 * SZ);
    unsigned short* Wqb = (unsigned short*)(ws + 6 * SZ);
    unsigned short* Wkb = (unsigned short*)(ws + 6 * SZ + 2u * 1024 * 1024);
    unsigned short* Wvb = (unsigned short*)(ws + 6 * SZ + 4u * 1024 * 1024);
    int* msflag         = (int*)(ws + 6 * SZ + 6u * 1024 * 1024);
    uint32_t* PM        = (uint32_t*)(ws + 6 * SZ + 8u * 1024 * 1024);  // 1 MB
    // TR (32 MB f32) reuses the Xq/Xk region — written only AFTER projections finish.
    float* TR = (float*)(ws + 3 * SZ);

    detect_mask<<<1, 64, 0, stream>>>((const unsigned int*)mask, msflag);

    const int nX8 = NB * NS * ND / 8;
    const int nW8 = 1024 * 1024 / 8;
    cvt_kernel<<<1024, 256, 0, stream>>>(query, (u16x8*)Xq, nX8);
    cvt_kernel<<<1024, 256, 0, stream>>>(key,   (u16x8*)Xk, nX8);
    cvt_kernel<<<1024, 256, 0, stream>>>(value, (u16x8*)Xv, nX8);
    cvt_kernel<<<256, 256, 0, stream>>>(Wq, (u16x8*)Wqb, nW8);
    cvt_kernel<<<256, 256, 0, stream>>>(Wk, (u16x8*)Wkb, nW8);
    cvt_kernel<<<256, 256, 0, stream>>>(Wv, (u16x8*)Wvb, nW8);

    dim3 pg(64, 8);
    proj_gemm<<<pg, 256, 0, stream>>>(Xq, Wqb, bq, Qbf, 0);
    proj_gemm<<<pg, 256, 0, stream>>>(Xk, Wkb, bk, Kbf, 0);
    proj_gemm<<<pg, 256, 0, stream>>>(Xv, Wvb, bv, Vt, 1);

    tr_kernel<<<NB * NS, 256, 0, stream>>>(rel, ts, mask, msflag, l1p, l2p, TR, PM);

    float* outp = (float*)d_out;
    float* probOut = outp + (size_t)NB * NS * ND;
    att_kernel<<<NB * NH * (NS / 16), 256, 0, stream>>>(Qbf, Kbf, PM, TR, l1p, l2p, probOut);
    pv_kernel<<<NB * NH * (NS / 64), 256, 0, stream>>>(probOut, Vt, outp);
}

// Round 3
// 699.411 us; speedup vs baseline: 1.3488x; 1.1171x over previous
//
#include <hip/hip_runtime.h>
#include <stdint.h>

typedef short bf16x8 __attribute__((ext_vector_type(8)));
typedef float f32x4 __attribute__((ext_vector_type(4)));
typedef unsigned short u16x4 __attribute__((ext_vector_type(4)));
typedef unsigned short u16x8 __attribute__((ext_vector_type(8)));

constexpr int NB = 8, NS = 1024, ND = 1024, NH = 16, NHD = 64;

static __device__ __forceinline__ unsigned short f2bf(float f) {
    union { float f; uint32_t u; } v; v.f = f;
    uint32_t r = (v.u + 0x7fffu + ((v.u >> 16) & 1u)) >> 16;
    return (unsigned short)r;
}

static __device__ __forceinline__ bool mask_at(const void* m, size_t idx, int ms) {
    if (ms == 4) return ((const unsigned int*)m)[idx] != 0u;
    return ((const unsigned char*)m)[idx] != 0;
}

__global__ void detect_mask(const unsigned int* __restrict__ m, int* __restrict__ flag) {
    int l = threadIdx.x;
    bool bad = false;
    for (int i = l; i < 1024; i += 64) {
        unsigned int w = m[i];
        bad |= (w > 1u && w != 0x3f800000u);
    }
    bad = (bool)__any(bad);
    if (l == 0) *flag = bad ? 1 : 4;
}

__global__ __launch_bounds__(256) void cvt_kernel(const float* __restrict__ in,
                                                  u16x8* __restrict__ out, int n8) {
    int stride = gridDim.x * blockDim.x;
    for (int idx = blockIdx.x * blockDim.x + threadIdx.x; idx < n8; idx += stride) {
        const float4* p = (const float4*)in + 2 * (size_t)idx;
        float4 a = p[0], b = p[1];
        u16x8 o;
        o[0] = f2bf(a.x); o[1] = f2bf(a.y); o[2] = f2bf(a.z); o[3] = f2bf(a.w);
        o[4] = f2bf(b.x); o[5] = f2bf(b.y); o[6] = f2bf(b.z); o[7] = f2bf(b.w);
        out[idx] = o;
    }
}

// C(M x N) = A(M x K, bf16 rm) * Bw(N x K, bf16 rm)^T + bias
// mode 0: C bf16 row-major (b,s,d).  mode 1: transposed Vt[b,h,d,s] bf16.
__global__ __launch_bounds__(256) void proj_gemm(const unsigned short* __restrict__ A,
                                                 const unsigned short* __restrict__ Bw,
                                                 const float* __restrict__ bias,
                                                 unsigned short* __restrict__ C, int mode) {
    int l = threadIdx.x & 63, w = threadIdx.x >> 6;
    int lr = l & 15, lg = l >> 4;
    int m_base = blockIdx.x * 128 + (w >> 1) * 64;
    int n_base = blockIdx.y * 128 + (w & 1) * 64;
    f32x4 acc[4][4] = {};
    for (int k = 0; k < 1024; k += 32) {
        bf16x8 af[4], bfr[4];
        #pragma unroll
        for (int mt = 0; mt < 4; mt++)
            af[mt] = *(const bf16x8*)(A + (size_t)(m_base + mt * 16 + lr) * 1024 + k + lg * 8);
        #pragma unroll
        for (int nt = 0; nt < 4; nt++)
            bfr[nt] = *(const bf16x8*)(Bw + (size_t)(n_base + nt * 16 + lr) * 1024 + k + lg * 8);
        #pragma unroll
        for (int mt = 0; mt < 4; mt++) {
            #pragma unroll
            for (int nt = 0; nt < 4; nt++)
                acc[mt][nt] = __builtin_amdgcn_mfma_f32_16x16x32_bf16(af[mt], bfr[nt], acc[mt][nt], 0, 0, 0);
        }
    }
    #pragma unroll
    for (int mt = 0; mt < 4; mt++) {
        #pragma unroll
        for (int nt = 0; nt < 4; nt++) {
            int col = n_base + nt * 16 + lr;
            int row0 = m_base + mt * 16 + lg * 4;
            float bv = bias[col];
            if (mode == 0) {
                #pragma unroll
                for (int r = 0; r < 4; r++)
                    C[(size_t)(row0 + r) * 1024 + col] = f2bf(acc[mt][nt][r] + bv);
            } else {
                int bb = row0 >> 10, s0 = row0 & 1023;
                int hh = col >> 6, dd = col & 63;
                u16x4 pk;
                #pragma unroll
                for (int r = 0; r < 4; r++) pk[r] = f2bf(acc[mt][nt][r] + bv);
                *(u16x4*)(C + ((size_t)((bb * NH + hh) * NHD + dd)) * NS + s0) = pk;
            }
        }
    }
}

// TR[b,q,k] = (1-l1)*l2 * time_attn + l1 * rel_attn  (shared by all heads)
// Also emits PM[b,q][k/32] packed mask bits (bit=1 -> masked).
__global__ __launch_bounds__(256) void tr_kernel(const float* __restrict__ rel,
                                                 const float* __restrict__ ts,
                                                 const void* __restrict__ maskp,
                                                 const int* __restrict__ msflag,
                                                 const float* __restrict__ l1p,
                                                 const float* __restrict__ l2p,
                                                 float* __restrict__ TR,
                                                 uint32_t* __restrict__ PM) {
    __shared__ float s_tm[4], s_rm[4], s_ts[4], s_rs[4];
    __shared__ unsigned char s_nib[256];
    int row = blockIdx.x;               // b*S + q
    int t = threadIdx.x, w = t >> 6, l = t & 63;
    int ms = *msflag;
    size_t base = (size_t)row * NS;
    float4 r4 = ((const float4*)(rel + base))[t];
    float4 t4 = ((const float4*)(ts + base))[t];
    float rr[4], tt[4];
    *(float4*)rr = r4; *(float4*)tt = t4;
    float tv[4], rv[4];
    unsigned nib = 0;
    float tmx = -3.0e38f, rmx = -3.0e38f;
    #pragma unroll
    for (int j = 0; j < 4; j++) {
        bool m = mask_at(maskp, base + t * 4 + j, ms);
        nib |= (m ? 1u : 0u) << j;
        tv[j] = m ? -100000.0f : __expf(-fabsf(tt[j]));
        float rm_ = m ? rr[j] : 0.0f;
        rv[j] = (rm_ == 0.0f) ? -100000.0f : rm_;
        tmx = fmaxf(tmx, tv[j]); rmx = fmaxf(rmx, rv[j]);
    }
    s_nib[t] = (unsigned char)nib;
    #pragma unroll
    for (int off = 1; off < 64; off <<= 1) {
        tmx = fmaxf(tmx, __shfl_xor(tmx, off));
        rmx = fmaxf(rmx, __shfl_xor(rmx, off));
    }
    if (l == 0) { s_tm[w] = tmx; s_rm[w] = rmx; }
    __syncthreads();
    tmx = fmaxf(fmaxf(s_tm[0], s_tm[1]), fmaxf(s_tm[2], s_tm[3]));
    rmx = fmaxf(fmaxf(s_rm[0], s_rm[1]), fmaxf(s_rm[2], s_rm[3]));
    float te[4], re[4], tsum = 0.f, rsum = 0.f;
    #pragma unroll
    for (int j = 0; j < 4; j++) {
        te[j] = __expf(tv[j] - tmx); tsum += te[j];
        re[j] = __expf(rv[j] - rmx); rsum += re[j];
    }
    #pragma unroll
    for (int off = 1; off < 64; off <<= 1) {
        tsum += __shfl_xor(tsum, off);
        rsum += __shfl_xor(rsum, off);
    }
    if (l == 0) { s_ts[w] = tsum; s_rs[w] = rsum; }
    __syncthreads();
    tsum = s_ts[0] + s_ts[1] + s_ts[2] + s_ts[3];
    rsum = s_rs[0] + s_rs[1] + s_rs[2] + s_rs[3];
    float l1 = *l1p, l2 = *l2p;
    float ti = ((1.0f - l1) * l2) / tsum;
    float ri = l1 / rsum;
    float4 o;
    o.x = te[0] * ti + re[0] * ri;
    o.y = te[1] * ti + re[1] * ri;
    o.z = te[2] * ti + re[2] * ri;
    o.w = te[3] * ti + re[3] * ri;
    ((float4*)(TR + base))[t] = o;
    if (t < 32) {
        uint32_t word = 0;
        #pragma unroll
        for (int i = 0; i < 8; i++)
            word |= ((uint32_t)s_nib[t * 8 + i]) << (i * 4);
        PM[(size_t)row * 32 + t] = word;
    }
}

// Fused scores+softmax+blend+PV. Block = (b, h, 16 q-rows).
// Phase 1 (swapped QK^T): wave w owns k in [w*256, w*256+256); lane owns q-row q0+lr.
// Phase 2: P (bf16) staged in swizzled LDS; wave w contracts full k for d-slice w*16..w*16+16.
__global__ __launch_bounds__(256) void att_pv_kernel(const unsigned short* __restrict__ Qb,
                                                     const unsigned short* __restrict__ Kb,
                                                     const uint32_t* __restrict__ PM,
                                                     const float* __restrict__ TR,
                                                     const float* __restrict__ l1p,
                                                     const float* __restrict__ l2p,
                                                     const unsigned short* __restrict__ Vt,
                                                     float* __restrict__ probOut,
                                                     float* __restrict__ outp) {
    __shared__ float redm[4][16];
    __shared__ float reds[4][16];
    __shared__ unsigned short P_lds[16 * 1024];   // 32 KB, XOR-swizzled
    int bid = blockIdx.x;
    int qt = bid & 63;
    int h = (bid >> 6) & 15;
    int b = bid >> 10;
    int tid = threadIdx.x, w = tid >> 6, l = tid & 63, lr = l & 15, lg = l >> 4;
    int q0 = qt * 16;
    int k_base = w * 256;
    int q = q0 + lr;                      // this lane's q-row (phase 1)
    size_t browq = (size_t)b * NS + q;

    // Q fragment (B operand): rows = q0+lr
    const unsigned short* qp = Qb + ((size_t)b * NS + q0 + lr) * ND + h * NHD + lg * 8;
    bf16x8 bq0 = *(const bf16x8*)qp;
    bf16x8 bq1 = *(const bf16x8*)(qp + 32);

    // packed mask words for this lane's q-row, k in [k_base, k_base+256)
    uint32_t pm[8];
    const uint32_t* pmrow = PM + browq * 32 + (k_base >> 5);
    #pragma unroll
    for (int j = 0; j < 8; j++) pm[j] = pmrow[j];

    f32x4 acc[16] = {};
    #pragma unroll
    for (int t = 0; t < 16; t++) {
        int k0 = k_base + t * 16;
        const unsigned short* kp = Kb + ((size_t)b * NS + k0 + lr) * ND + h * NHD + lg * 8;
        bf16x8 a0 = *(const bf16x8*)kp;
        bf16x8 a1 = *(const bf16x8*)(kp + 32);
        acc[t] = __builtin_amdgcn_mfma_f32_16x16x32_bf16(a0, bq0, acc[t], 0, 0, 0);
        acc[t] = __builtin_amdgcn_mfma_f32_16x16x32_bf16(a1, bq1, acc[t], 0, 0, 0);
    }
    // scale + mask
    #pragma unroll
    for (int t = 0; t < 16; t++) {
        uint32_t word = pm[t >> 1];
        int shift = (t & 1) * 16 + lg * 4;
        #pragma unroll
        for (int r = 0; r < 4; r++) {
            bool m = (word >> (shift + r)) & 1u;
            acc[t][r] = m ? -1.0e32f : acc[t][r] * 0.125f;
        }
    }
    // row max
    float mx = acc[0][0];
    #pragma unroll
    for (int t = 0; t < 16; t++) {
        #pragma unroll
        for (int r = 0; r < 4; r++) mx = fmaxf(mx, acc[t][r]);
    }
    mx = fmaxf(mx, __shfl_xor(mx, 16));
    mx = fmaxf(mx, __shfl_xor(mx, 32));
    if (l < 16) redm[w][l] = mx;
    __syncthreads();
    float rowmax = fmaxf(fmaxf(redm[0][lr], redm[1][lr]), fmaxf(redm[2][lr], redm[3][lr]));
    // exp + row sum
    float sm = 0.f;
    #pragma unroll
    for (int t = 0; t < 16; t++) {
        #pragma unroll
        for (int r = 0; r < 4; r++) {
            float e = __expf(acc[t][r] - rowmax);
            acc[t][r] = e;
            sm += e;
        }
    }
    sm += __shfl_xor(sm, 16);
    sm += __shfl_xor(sm, 32);
    if (l < 16) reds[w][l] = sm;
    __syncthreads();
    float total = reds[0][lr] + reds[1][lr] + reds[2][lr] + reds[3][lr];
    float l1 = *l1p, l2 = *l2p;
    float rinv = ((1.0f - l1) * (1.0f - l2)) / total;

    // blend + store f32 prob + stage bf16 P into swizzled LDS
    float* po = probOut + ((size_t)(b * NH + h)) * NS * NS + (size_t)q * NS;
    const float* trrow = TR + browq * NS;
    uint32_t swz_w = (uint32_t)((q & 7) << 4);
    #pragma unroll
    for (int t = 0; t < 16; t++) {
        int kc = k_base + t * 16 + lg * 4;
        float4 tr4 = *(const float4*)(trrow + kc);
        float4 o;
        o.x = acc[t][0] * rinv + tr4.x;
        o.y = acc[t][1] * rinv + tr4.y;
        o.z = acc[t][2] * rinv + tr4.z;
        o.w = acc[t][3] * rinv + tr4.w;
        *(float4*)(po + kc) = o;
        u16x4 pk;
        pk[0] = f2bf(o.x); pk[1] = f2bf(o.y); pk[2] = f2bf(o.z); pk[3] = f2bf(o.w);
        uint32_t waddr = ((uint32_t)(lr * 2048 + kc * 2)) ^ swz_w;
        *(u16x4*)((char*)P_lds + waddr) = pk;
    }
    __syncthreads();

    // Phase 2: PV. Wave w owns d-slice [w*16, w*16+16); contract full k=1024.
    // A = V fragment (d rows = lr), B = P from LDS (q cols = lr).
    const unsigned short* vt = Vt + (((size_t)(b * NH + h)) * NHD + w * 16 + lr) * NS;
    uint32_t swz_r = (uint32_t)((lr & 7) << 4);
    f32x4 acc2 = {};
    #pragma unroll 4
    for (int ks = 0; ks < 32; ks++) {
        int k0 = ks * 32;
        bf16x8 vfrag = *(const bf16x8*)(vt + k0 + lg * 8);
        uint32_t raddr = ((uint32_t)(lr * 2048 + (k0 + lg * 8) * 2)) ^ swz_r;
        bf16x8 pfrag = *(const bf16x8*)((const char*)P_lds + raddr);
        acc2 = __builtin_amdgcn_mfma_f32_16x16x32_bf16(vfrag, pfrag, acc2, 0, 0, 0);
    }
    // D: lane axis (lr) = q, reg axis (lg*4+r) = d_local
    float4 ov;
    ov.x = acc2[0]; ov.y = acc2[1]; ov.z = acc2[2]; ov.w = acc2[3];
    *(float4*)(outp + ((size_t)b * NS + q0 + lr) * ND + h * NHD + w * 16 + lg * 4) = ov;
}

extern "C" void kernel_launch(void* const* d_in, const int* in_sizes, int n_in,
                              void* d_out, int out_size, void* d_ws, size_t ws_size,
                              hipStream_t stream) {
    const float* query = (const float*)d_in[0];
    const float* key   = (const float*)d_in[1];
    const float* value = (const float*)d_in[2];
    const float* rel   = (const float*)d_in[3];
    const float* ts    = (const float*)d_in[4];
    const void*  mask  = d_in[5];
    const float* l1p   = (const float*)d_in[6];
    const float* l2p   = (const float*)d_in[7];
    const float* Wq = (const float*)d_in[9];
    const float* bq = (const float*)d_in[10];
    const float* Wk = (const float*)d_in[11];
    const float* bk = (const float*)d_in[12];
    const float* Wv = (const float*)d_in[13];
    const float* bv = (const float*)d_in[14];

    char* ws = (char*)d_ws;
    const size_t SZ = (size_t)NB * NS * ND * 2;   // 16.78 MB
    unsigned short* Qbf = (unsigned short*)(ws);
    unsigned short* Kbf = (unsigned short*)(ws + SZ);
    unsigned short* Vt  = (unsigned short*)(ws + 2 * SZ);
    unsigned short* Xq  = (unsigned short*)(ws + 3 * SZ);
    unsigned short* Xk  = (unsigned short*)(ws + 4 * SZ);
    unsigned short* Xv  = (unsigned short*)(ws + 5 * SZ);
    unsigned short* Wqb = (unsigned short*)(ws + 6 * SZ);
    unsigned short* Wkb = (unsigned short*)(ws + 6 * SZ + 2u * 1024 * 1024);
    unsigned short* Wvb = (unsigned short*)(ws + 6 * SZ + 4u * 1024 * 1024);
    int* msflag         = (int*)(ws + 6 * SZ + 6u * 1024 * 1024);
    uint32_t* PM        = (uint32_t*)(ws + 6 * SZ + 8u * 1024 * 1024);  // 1 MB
    // TR (32 MB f32) reuses the Xq/Xk region — written only AFTER projections finish.
    float* TR = (float*)(ws + 3 * SZ);

    detect_mask<<<1, 64, 0, stream>>>((const unsigned int*)mask, msflag);

    const int nX8 = NB * NS * ND / 8;
    const int nW8 = 1024 * 1024 / 8;
    cvt_kernel<<<1024, 256, 0, stream>>>(query, (u16x8*)Xq, nX8);
    cvt_kernel<<<1024, 256, 0, stream>>>(key,   (u16x8*)Xk, nX8);
    cvt_kernel<<<1024, 256, 0, stream>>>(value, (u16x8*)Xv, nX8);
    cvt_kernel<<<256, 256, 0, stream>>>(Wq, (u16x8*)Wqb, nW8);
    cvt_kernel<<<256, 256, 0, stream>>>(Wk, (u16x8*)Wkb, nW8);
    cvt_kernel<<<256, 256, 0, stream>>>(Wv, (u16x8*)Wvb, nW8);

    dim3 pg(64, 8);
    proj_gemm<<<pg, 256, 0, stream>>>(Xq, Wqb, bq, Qbf, 0);
    proj_gemm<<<pg, 256, 0, stream>>>(Xk, Wkb, bk, Kbf, 0);
    proj_gemm<<<pg, 256, 0, stream>>>(Xv, Wvb, bv, Vt, 1);

    tr_kernel<<<NB * NS, 256, 0, stream>>>(rel, ts, mask, msflag, l1p, l2p, TR, PM);

    float* outp = (float*)d_out;
    float* probOut = outp + (size_t)NB * NS * ND;
    att_pv_kernel<<<NB * NH * (NS / 16), 256, 0, stream>>>(Qbf, Kbf, PM, TR, l1p, l2p, Vt,
                                                           probOut, outp);
}

// Round 4
// 621.324 us; speedup vs baseline: 1.5183x; 1.1257x over previous
//
#include <hip/hip_runtime.h>
#include <stdint.h>

typedef short bf16x8 __attribute__((ext_vector_type(8)));
typedef float f32x4 __attribute__((ext_vector_type(4)));
typedef unsigned short u16x4 __attribute__((ext_vector_type(4)));
typedef unsigned short u16x8 __attribute__((ext_vector_type(8)));

constexpr int NB = 8, NS = 1024, ND = 1024, NH = 16, NHD = 64;

static __device__ __forceinline__ unsigned short f2bf(float f) {
    union { float f; uint32_t u; } v; v.f = f;
    uint32_t r = (v.u + 0x7fffu + ((v.u >> 16) & 1u)) >> 16;
    return (unsigned short)r;
}

static __device__ __forceinline__ bool mask_at(const void* m, size_t idx, int ms) {
    if (ms == 4) return ((const unsigned int*)m)[idx] != 0u;
    return ((const unsigned char*)m)[idx] != 0;
}

__global__ void detect_mask(const unsigned int* __restrict__ m, int* __restrict__ flag) {
    int l = threadIdx.x;
    bool bad = false;
    for (int i = l; i < 1024; i += 64) {
        unsigned int w = m[i];
        bad |= (w > 1u && w != 0x3f800000u);
    }
    bad = (bool)__any(bad);
    if (l == 0) *flag = bad ? 1 : 4;
}

// f32 [M][1024] -> fragment-packed bf16 [M/16][32 kt][64 lane][8]
// lane = (m%16) + 16*((k%32)/8), e = k%8. Reads coalesced float4 pairs.
__global__ __launch_bounds__(256) void cvt_frag(const float* __restrict__ in,
                                                unsigned short* __restrict__ out, int n8) {
    int stride = gridDim.x * blockDim.x;
    for (int idx = blockIdx.x * blockDim.x + threadIdx.x; idx < n8; idx += stride) {
        const float4* p = (const float4*)in + 2 * (size_t)idx;
        float4 a = p[0], b = p[1];
        u16x8 o;
        o[0] = f2bf(a.x); o[1] = f2bf(a.y); o[2] = f2bf(a.z); o[3] = f2bf(a.w);
        o[4] = f2bf(b.x); o[5] = f2bf(b.y); o[6] = f2bf(b.z); o[7] = f2bf(b.w);
        int m = idx >> 7, c8 = idx & 127;          // row, 8-elem chunk within row
        int kt = c8 >> 2, sub = c8 & 3;
        int lane = (m & 15) + 16 * sub;
        size_t slot = ((size_t)(m >> 4) * 32 + kt) * 64 + lane;
        *(u16x8*)(out + slot * 8) = o;
    }
}

// C(M x N) = A(MxK)*W(NxK)^T + bias, inputs fragment-packed [*/16][32][64][8].
// mode 0: write QKf[b][h][s/16][d32][64][8]   (A/B-frag layout for QK^T)
// mode 1: write Vf [b][h][s/32][dt4][64][8]   (A-frag layout for PV, k-dim = s)
__global__ __launch_bounds__(256) void proj_gemm(const unsigned short* __restrict__ Af,
                                                 const unsigned short* __restrict__ Wf,
                                                 const float* __restrict__ bias,
                                                 unsigned short* __restrict__ C, int mode) {
    int l = threadIdx.x & 63, w = threadIdx.x >> 6;
    int lr = l & 15, lg = l >> 4;
    int m_base = blockIdx.x * 128 + (w >> 1) * 64;
    int n_base = blockIdx.y * 128 + (w & 1) * 64;
    int mtg0 = m_base >> 4, ntg0 = n_base >> 4;
    f32x4 acc[4][4] = {};
    for (int kt = 0; kt < 32; kt++) {
        bf16x8 af[4], bfr[4];
        #pragma unroll
        for (int mt = 0; mt < 4; mt++)
            af[mt] = *(const bf16x8*)(Af + (((size_t)(mtg0 + mt) * 32 + kt) * 64 + l) * 8);
        #pragma unroll
        for (int nt = 0; nt < 4; nt++)
            bfr[nt] = *(const bf16x8*)(Wf + (((size_t)(ntg0 + nt) * 32 + kt) * 64 + l) * 8);
        #pragma unroll
        for (int mt = 0; mt < 4; mt++) {
            #pragma unroll
            for (int nt = 0; nt < 4; nt++)
                acc[mt][nt] = __builtin_amdgcn_mfma_f32_16x16x32_bf16(af[mt], bfr[nt], acc[mt][nt], 0, 0, 0);
        }
    }
    #pragma unroll
    for (int mt = 0; mt < 4; mt++) {
        #pragma unroll
        for (int nt = 0; nt < 4; nt++) {
            int col = n_base + nt * 16 + lr;          // output feature n
            int row0 = m_base + mt * 16 + lg * 4;     // flattened (b*S + s)
            float bv = bias[col];
            int b = row0 >> 10;
            int h = col >> 6;
            if (mode == 0) {
                int st = (row0 & 1023) >> 4;
                int d32 = (col & 63) >> 5;
                int sub = (col & 31) >> 3;
                int e = col & 7;
                size_t base = ((((size_t)(b * NH + h) * 64 + st) * 2 + d32) * 64) * 8;
                #pragma unroll
                for (int r = 0; r < 4; r++) {
                    int lane = lg * 4 + r + 16 * sub;
                    C[base + (size_t)lane * 8 + e] = f2bf(acc[mt][nt][r] + bv);
                }
            } else {
                int s0 = row0 & 1023;
                int ks = s0 >> 5;
                int dd = col & 63;
                int dt = dd >> 4;
                int lane = (dd & 15) + 16 * ((s0 & 31) >> 3);
                u16x4 pk;
                #pragma unroll
                for (int r = 0; r < 4; r++) pk[r] = f2bf(acc[mt][nt][r] + bv);
                size_t base = ((((size_t)(b * NH + h) * 32 + ks) * 4 + dt) * 64 + lane) * 8 + (lg & 1) * 4;
                *(u16x4*)(C + base) = pk;
            }
        }
    }
}

// TR = (1-l1)*l2*time_attn + l1*rel_attn, written fragment-packed:
// TRf[b][qt][w4][t16][lane64][4f]  lane = (q&15)+16*lg, covers k = w*256+t*16+lg*4+j
// PMf[b][qt][w4][lr16][8 words]    packed mask bits for k in [w*256, w*256+256)
__global__ __launch_bounds__(256) void tr_kernel(const float* __restrict__ rel,
                                                 const float* __restrict__ ts,
                                                 const void* __restrict__ maskp,
                                                 const int* __restrict__ msflag,
                                                 const float* __restrict__ l1p,
                                                 const float* __restrict__ l2p,
                                                 float* __restrict__ TRf,
                                                 uint32_t* __restrict__ PMf) {
    __shared__ float s_tm[4], s_rm[4], s_ts[4], s_rs[4];
    __shared__ unsigned char s_nib[256];
    int row = blockIdx.x;               // b*S + q
    int t = threadIdx.x, w = t >> 6, l = t & 63;
    int ms = *msflag;
    size_t base = (size_t)row * NS;
    float4 r4 = ((const float4*)(rel + base))[t];
    float4 t4 = ((const float4*)(ts + base))[t];
    float rr[4], tt[4];
    *(float4*)rr = r4; *(float4*)tt = t4;
    float tv[4], rv[4];
    unsigned nib = 0;
    float tmx = -3.0e38f, rmx = -3.0e38f;
    #pragma unroll
    for (int j = 0; j < 4; j++) {
        bool m = mask_at(maskp, base + t * 4 + j, ms);
        nib |= (m ? 1u : 0u) << j;
        tv[j] = m ? -100000.0f : __expf(-fabsf(tt[j]));
        float rm_ = m ? rr[j] : 0.0f;
        rv[j] = (rm_ == 0.0f) ? -100000.0f : rm_;
        tmx = fmaxf(tmx, tv[j]); rmx = fmaxf(rmx, rv[j]);
    }
    s_nib[t] = (unsigned char)nib;
    #pragma unroll
    for (int off = 1; off < 64; off <<= 1) {
        tmx = fmaxf(tmx, __shfl_xor(tmx, off));
        rmx = fmaxf(rmx, __shfl_xor(rmx, off));
    }
    if (l == 0) { s_tm[w] = tmx; s_rm[w] = rmx; }
    __syncthreads();
    tmx = fmaxf(fmaxf(s_tm[0], s_tm[1]), fmaxf(s_tm[2], s_tm[3]));
    rmx = fmaxf(fmaxf(s_rm[0], s_rm[1]), fmaxf(s_rm[2], s_rm[3]));
    float te[4], re[4], tsum = 0.f, rsum = 0.f;
    #pragma unroll
    for (int j = 0; j < 4; j++) {
        te[j] = __expf(tv[j] - tmx); tsum += te[j];
        re[j] = __expf(rv[j] - rmx); rsum += re[j];
    }
    #pragma unroll
    for (int off = 1; off < 64; off <<= 1) {
        tsum += __shfl_xor(tsum, off);
        rsum += __shfl_xor(rsum, off);
    }
    if (l == 0) { s_ts[w] = tsum; s_rs[w] = rsum; }
    __syncthreads();
    tsum = s_ts[0] + s_ts[1] + s_ts[2] + s_ts[3];
    rsum = s_rs[0] + s_rs[1] + s_rs[2] + s_rs[3];
    float l1 = *l1p, l2 = *l2p;
    float ti = ((1.0f - l1) * l2) / tsum;
    float ri = l1 / rsum;
    float4 o;
    o.x = te[0] * ti + re[0] * ri;
    o.y = te[1] * ti + re[1] * ri;
    o.z = te[2] * ti + re[2] * ri;
    o.w = te[3] * ti + re[3] * ri;
    int b = row >> 10, q = row & 1023;
    int qt = q >> 4, qr = q & 15;
    // this thread's float4 covers k = t*4..t*4+3: w4 = t>>6, tt = (t>>2)&15, lgq = t&3
    size_t slot = ((((size_t)(b * 64 + qt) * 4 + (t >> 6)) * 16 + ((t >> 2) & 15)) * 64
                   + (qr + 16 * (t & 3)));
    ((float4*)TRf)[slot] = o;
    if (t < 32) {
        uint32_t word = 0;
        #pragma unroll
        for (int i = 0; i < 8; i++)
            word |= ((uint32_t)s_nib[t * 8 + i]) << (i * 4);
        // word covers k = t*32..t*32+31: w = t>>3, wd = t&7
        PMf[(((size_t)(b * 64 + qt) * 4 + (t >> 3)) * 16 + qr) * 8 + (t & 7)] = word;
    }
}

// Fused scores+softmax+blend+PV, all operand loads coalesced via fragment-packed layouts.
__global__ __launch_bounds__(256) void att_pv_kernel(const unsigned short* __restrict__ Qf,
                                                     const unsigned short* __restrict__ Kf,
                                                     const uint32_t* __restrict__ PMf,
                                                     const float* __restrict__ TRf,
                                                     const float* __restrict__ l1p,
                                                     const float* __restrict__ l2p,
                                                     const unsigned short* __restrict__ Vf,
                                                     float* __restrict__ probOut,
                                                     float* __restrict__ outp) {
    __shared__ float redm[4][16];
    __shared__ float reds[4][16];
    __shared__ unsigned short P_lds[16 * 1024];   // 32 KB, XOR-swizzled
    int bid = blockIdx.x;
    int qt = bid & 63;
    int h = (bid >> 6) & 15;
    int b = bid >> 10;
    int tid = threadIdx.x, w = tid >> 6, l = tid & 63, lr = l & 15, lg = l >> 4;
    int q0 = qt * 16;
    int k_base = w * 256;
    int q = q0 + lr;
    size_t bh = (size_t)(b * NH + h);

    // Q fragments (B operand), coalesced: lane l reads slot l
    const unsigned short* qf = Qf + (((bh * 64 + qt) * 2) * 64 + l) * 8;
    bf16x8 bq0 = *(const bf16x8*)(qf);
    bf16x8 bq1 = *(const bf16x8*)(qf + 64 * 8);

    // packed mask: 8 words, lanes lg broadcast
    const uint32_t* pmp = PMf + (((size_t)(b * 64 + qt) * 4 + w) * 16 + lr) * 8;
    uint32_t pm[8];
    *(uint4*)(pm) = *(const uint4*)(pmp);
    *(uint4*)(pm + 4) = *(const uint4*)(pmp + 4);

    f32x4 acc[16] = {};
    const unsigned short* kfb = Kf + (((bh * 64 + w * 16) * 2) * 64) * 8 + (size_t)l * 8;
    #pragma unroll
    for (int t = 0; t < 16; t++) {
        const unsigned short* kp = kfb + (size_t)t * 2 * 64 * 8;
        bf16x8 a0 = *(const bf16x8*)(kp);
        bf16x8 a1 = *(const bf16x8*)(kp + 64 * 8);
        acc[t] = __builtin_amdgcn_mfma_f32_16x16x32_bf16(a0, bq0, acc[t], 0, 0, 0);
        acc[t] = __builtin_amdgcn_mfma_f32_16x16x32_bf16(a1, bq1, acc[t], 0, 0, 0);
    }
    // scale + mask
    #pragma unroll
    for (int t = 0; t < 16; t++) {
        uint32_t word = pm[t >> 1];
        int shift = (t & 1) * 16 + lg * 4;
        #pragma unroll
        for (int r = 0; r < 4; r++) {
            bool m = (word >> (shift + r)) & 1u;
            acc[t][r] = m ? -1.0e32f : acc[t][r] * 0.125f;
        }
    }
    // row max
    float mx = acc[0][0];
    #pragma unroll
    for (int t = 0; t < 16; t++) {
        #pragma unroll
        for (int r = 0; r < 4; r++) mx = fmaxf(mx, acc[t][r]);
    }
    mx = fmaxf(mx, __shfl_xor(mx, 16));
    mx = fmaxf(mx, __shfl_xor(mx, 32));
    if (l < 16) redm[w][l] = mx;
    __syncthreads();
    float rowmax = fmaxf(fmaxf(redm[0][lr], redm[1][lr]), fmaxf(redm[2][lr], redm[3][lr]));
    // exp + row sum
    float sm = 0.f;
    #pragma unroll
    for (int t = 0; t < 16; t++) {
        #pragma unroll
        for (int r = 0; r < 4; r++) {
            float e = __expf(acc[t][r] - rowmax);
            acc[t][r] = e;
            sm += e;
        }
    }
    sm += __shfl_xor(sm, 16);
    sm += __shfl_xor(sm, 32);
    if (l < 16) reds[w][l] = sm;
    __syncthreads();
    float total = reds[0][lr] + reds[1][lr] + reds[2][lr] + reds[3][lr];
    float l1 = *l1p, l2 = *l2p;
    float rinv = ((1.0f - l1) * (1.0f - l2)) / total;

    // blend + store f32 prob + stage bf16 P into swizzled LDS
    float* po = probOut + bh * NS * NS + (size_t)q * NS;
    const float* trf = TRf + ((((size_t)(b * 64 + qt) * 4 + w) * 16) * 64 + l) * 4;
    uint32_t swz_w = (uint32_t)((q & 7) << 4);
    #pragma unroll
    for (int t = 0; t < 16; t++) {
        int kc = k_base + t * 16 + lg * 4;
        float4 tr4 = *(const float4*)(trf + (size_t)t * 64 * 4);
        float4 o;
        o.x = acc[t][0] * rinv + tr4.x;
        o.y = acc[t][1] * rinv + tr4.y;
        o.z = acc[t][2] * rinv + tr4.z;
        o.w = acc[t][3] * rinv + tr4.w;
        *(float4*)(po + kc) = o;
        u16x4 pk;
        pk[0] = f2bf(o.x); pk[1] = f2bf(o.y); pk[2] = f2bf(o.z); pk[3] = f2bf(o.w);
        uint32_t waddr = ((uint32_t)(lr * 2048 + kc * 2)) ^ swz_w;
        *(u16x4*)((char*)P_lds + waddr) = pk;
    }
    __syncthreads();

    // Phase 2: PV. Wave w owns d-slice [w*16, w*16+16); contract full k=1024.
    // A = V fragment (coalesced from Vf), B = P from LDS.
    const unsigned short* vf = Vf + ((bh * 32 * 4 + w) * 64 + l) * 8;   // [ks][dt=w][l]
    uint32_t swz_r = (uint32_t)((lr & 7) << 4);
    f32x4 acc2 = {};
    #pragma unroll 8
    for (int ks = 0; ks < 32; ks++) {
        int k0 = ks * 32;
        bf16x8 vfrag = *(const bf16x8*)(vf + (size_t)ks * 4 * 64 * 8);
        uint32_t raddr = ((uint32_t)(lr * 2048 + (k0 + lg * 8) * 2)) ^ swz_r;
        bf16x8 pfrag = *(const bf16x8*)((const char*)P_lds + raddr);
        acc2 = __builtin_amdgcn_mfma_f32_16x16x32_bf16(vfrag, pfrag, acc2, 0, 0, 0);
    }
    float4 ov;
    ov.x = acc2[0]; ov.y = acc2[1]; ov.z = acc2[2]; ov.w = acc2[3];
    *(float4*)(outp + ((size_t)b * NS + q0 + lr) * ND + h * NHD + w * 16 + lg * 4) = ov;
}

extern "C" void kernel_launch(void* const* d_in, const int* in_sizes, int n_in,
                              void* d_out, int out_size, void* d_ws, size_t ws_size,
                              hipStream_t stream) {
    const float* query = (const float*)d_in[0];
    const float* key   = (const float*)d_in[1];
    const float* value = (const float*)d_in[2];
    const float* rel   = (const float*)d_in[3];
    const float* ts    = (const float*)d_in[4];
    const void*  mask  = d_in[5];
    const float* l1p   = (const float*)d_in[6];
    const float* l2p   = (const float*)d_in[7];
    const float* Wq = (const float*)d_in[9];
    const float* bq = (const float*)d_in[10];
    const float* Wk = (const float*)d_in[11];
    const float* bk = (const float*)d_in[12];
    const float* Wv = (const float*)d_in[13];
    const float* bv = (const float*)d_in[14];

    char* ws = (char*)d_ws;
    const size_t SZ = (size_t)NB * NS * ND * 2;   // 16.78 MB
    unsigned short* Qf  = (unsigned short*)(ws);
    unsigned short* Kf  = (unsigned short*)(ws + SZ);
    unsigned short* Vf  = (unsigned short*)(ws + 2 * SZ);
    unsigned short* Afq = (unsigned short*)(ws + 3 * SZ);
    unsigned short* Afk = (unsigned short*)(ws + 4 * SZ);
    unsigned short* Afv = (unsigned short*)(ws + 5 * SZ);
    unsigned short* Wfq = (unsigned short*)(ws + 6 * SZ);
    unsigned short* Wfk = (unsigned short*)(ws + 6 * SZ + 2u * 1024 * 1024);
    unsigned short* Wfv = (unsigned short*)(ws + 6 * SZ + 4u * 1024 * 1024);
    int* msflag         = (int*)(ws + 6 * SZ + 6u * 1024 * 1024);
    uint32_t* PMf       = (uint32_t*)(ws + 6 * SZ + 8u * 1024 * 1024);  // 1 MB
    // TRf (33.55 MB = exactly 2*SZ) reuses Afq+Afk — written only AFTER projections finish.
    float* TRf = (float*)(ws + 3 * SZ);

    detect_mask<<<1, 64, 0, stream>>>((const unsigned int*)mask, msflag);

    const int nX8 = NB * NS * ND / 8;     // 1048576
    const int nW8 = 1024 * 1024 / 8;      // 131072
    cvt_frag<<<1024, 256, 0, stream>>>(query, Afq, nX8);
    cvt_frag<<<1024, 256, 0, stream>>>(key,   Afk, nX8);
    cvt_frag<<<1024, 256, 0, stream>>>(value, Afv, nX8);
    cvt_frag<<<256, 256, 0, stream>>>(Wq, Wfq, nW8);
    cvt_frag<<<256, 256, 0, stream>>>(Wk, Wfk, nW8);
    cvt_frag<<<256, 256, 0, stream>>>(Wv, Wfv, nW8);

    dim3 pg(64, 8);
    proj_gemm<<<pg, 256, 0, stream>>>(Afq, Wfq, bq, Qf, 0);
    proj_gemm<<<pg, 256, 0, stream>>>(Afk, Wfk, bk, Kf, 0);
    proj_gemm<<<pg, 256, 0, stream>>>(Afv, Wfv, bv, Vf, 1);

    tr_kernel<<<NB * NS, 256, 0, stream>>>(rel, ts, mask, msflag, l1p, l2p, TRf, PMf);

    float* outp = (float*)d_out;
    float* probOut = outp + (size_t)NB * NS * ND;
    att_pv_kernel<<<NB * NH * (NS / 16), 256, 0, stream>>>(Qf, Kf, PMf, TRf, l1p, l2p, Vf,
                                                           probOut, outp);
}

// Round 5
// 572.834 us; speedup vs baseline: 1.6469x; 1.0846x over previous
//
#include <hip/hip_runtime.h>
#include <stdint.h>

typedef short bf16x8 __attribute__((ext_vector_type(8)));
typedef short bf16x4 __attribute__((ext_vector_type(4)));
typedef float f32x4 __attribute__((ext_vector_type(4)));
typedef unsigned short u16x4 __attribute__((ext_vector_type(4)));
typedef unsigned short u16x8 __attribute__((ext_vector_type(8)));

constexpr int NB = 8, NS = 1024, ND = 1024, NH = 16, NHD = 64;

static __device__ __forceinline__ unsigned short f2bf(float f) {
    union { float f; uint32_t u; } v; v.f = f;
    uint32_t r = (v.u + 0x7fffu + ((v.u >> 16) & 1u)) >> 16;
    return (unsigned short)r;
}

static __device__ __forceinline__ f32x4 mfma32(bf16x8 a, bf16x8 b, f32x4 c) {
    return __builtin_amdgcn_mfma_f32_16x16x32_bf16(a, b, c, 0, 0, 0);
}

// K=16 bf16 MFMA: A/B frag = 4 bf16 (k = (l>>4)*4 + e), C/D = f32x4.
static __device__ __forceinline__ f32x4 mfma16(bf16x4 a, bf16x4 b, f32x4 c) {
#if __has_builtin(__builtin_amdgcn_mfma_f32_16x16x16bf16_1k)
    return __builtin_amdgcn_mfma_f32_16x16x16bf16_1k(a, b, c, 0, 0, 0);
#elif __has_builtin(__builtin_amdgcn_mfma_f32_16x16x16_bf16)
    return __builtin_amdgcn_mfma_f32_16x16x16_bf16(a, b, c, 0, 0, 0);
#else
    asm volatile("v_mfma_f32_16x16x16_bf16 %0, %1, %2, %0\n\ts_nop 7\n\ts_nop 7"
                 : "+v"(c) : "v"(a), "v"(b));
    return c;
#endif
}

static __device__ __forceinline__ bool mask_at(const void* m, size_t idx, int ms) {
    if (ms == 4) return ((const unsigned int*)m)[idx] != 0u;
    return ((const unsigned char*)m)[idx] != 0;
}

__global__ void detect_mask(const unsigned int* __restrict__ m, int* __restrict__ flag) {
    int l = threadIdx.x;
    bool bad = false;
    for (int i = l; i < 1024; i += 64) {
        unsigned int w = m[i];
        bad |= (w > 1u && w != 0x3f800000u);
    }
    bad = (bool)__any(bad);
    if (l == 0) *flag = bad ? 1 : 4;
}

// f32 [M][1024] -> fragment-packed bf16 [M/16][32 kt][64 lane][8]
__global__ __launch_bounds__(256) void cvt_frag(const float* __restrict__ in,
                                                unsigned short* __restrict__ out, int n8) {
    int stride = gridDim.x * blockDim.x;
    for (int idx = blockIdx.x * blockDim.x + threadIdx.x; idx < n8; idx += stride) {
        const float4* p = (const float4*)in + 2 * (size_t)idx;
        float4 a = p[0], b = p[1];
        u16x8 o;
        o[0] = f2bf(a.x); o[1] = f2bf(a.y); o[2] = f2bf(a.z); o[3] = f2bf(a.w);
        o[4] = f2bf(b.x); o[5] = f2bf(b.y); o[6] = f2bf(b.z); o[7] = f2bf(b.w);
        int m = idx >> 7, c8 = idx & 127;
        int kt = c8 >> 2, sub = c8 & 3;
        int lane = (m & 15) + 16 * sub;
        size_t slot = ((size_t)(m >> 4) * 32 + kt) * 64 + lane;
        *(u16x8*)(out + slot * 8) = o;
    }
}

// C(M x N) = A(MxK)*W(NxK)^T + bias, inputs fragment-packed [*/16][32][64][8].
// mode 0: QKf[b][h][s/16][d32][64][8]           (K=32 frag layout for QK^T)
// mode 1: Vf [b][h][w4][tp8][dt4][64][4+4]      (K=16 frag pairs for PV; k-dim = s)
__global__ __launch_bounds__(256) void proj_gemm(const unsigned short* __restrict__ Af,
                                                 const unsigned short* __restrict__ Wf,
                                                 const float* __restrict__ bias,
                                                 unsigned short* __restrict__ C, int mode) {
    int l = threadIdx.x & 63, w = threadIdx.x >> 6;
    int lr = l & 15, lg = l >> 4;
    int m_base = blockIdx.x * 128 + (w >> 1) * 64;
    int n_base = blockIdx.y * 128 + (w & 1) * 64;
    int mtg0 = m_base >> 4, ntg0 = n_base >> 4;
    f32x4 acc[4][4] = {};
    for (int kt = 0; kt < 32; kt++) {
        bf16x8 af[4], bfr[4];
        #pragma unroll
        for (int mt = 0; mt < 4; mt++)
            af[mt] = *(const bf16x8*)(Af + (((size_t)(mtg0 + mt) * 32 + kt) * 64 + l) * 8);
        #pragma unroll
        for (int nt = 0; nt < 4; nt++)
            bfr[nt] = *(const bf16x8*)(Wf + (((size_t)(ntg0 + nt) * 32 + kt) * 64 + l) * 8);
        #pragma unroll
        for (int mt = 0; mt < 4; mt++) {
            #pragma unroll
            for (int nt = 0; nt < 4; nt++)
                acc[mt][nt] = mfma32(af[mt], bfr[nt], acc[mt][nt]);
        }
    }
    #pragma unroll
    for (int mt = 0; mt < 4; mt++) {
        #pragma unroll
        for (int nt = 0; nt < 4; nt++) {
            int col = n_base + nt * 16 + lr;          // output feature n
            int row0 = m_base + mt * 16 + lg * 4;     // flattened (b*S + s)
            float bv = bias[col];
            int b = row0 >> 10;
            int h = col >> 6;
            if (mode == 0) {
                int st = (row0 & 1023) >> 4;
                int d32 = (col & 63) >> 5;
                int sub = (col & 31) >> 3;
                int e = col & 7;
                size_t base = ((((size_t)(b * NH + h) * 64 + st) * 2 + d32) * 64) * 8;
                #pragma unroll
                for (int r = 0; r < 4; r++) {
                    int lane = lg * 4 + r + 16 * sub;
                    C[base + (size_t)lane * 8 + e] = f2bf(acc[mt][nt][r] + bv);
                }
            } else {
                int s0 = row0 & 1023;        // lg*4-aligned
                int tg = s0 >> 4;            // global 16-k tile index
                int wv = tg >> 4;            // owning wave (k-slice) 0..3
                int t_in = tg & 15;
                int tp = t_in >> 1, half = t_in & 1;
                int dd = col & 63;
                int dt = dd >> 4;
                int lane = (dd & 15) + 16 * lg;
                u16x4 pk;
                #pragma unroll
                for (int r = 0; r < 4; r++) pk[r] = f2bf(acc[mt][nt][r] + bv);
                size_t addr = (((((size_t)(b * NH + h) * 4 + wv) * 8 + tp) * 4 + dt) * 64 + lane) * 8
                              + half * 4;
                *(u16x4*)(C + addr) = pk;
            }
        }
    }
}

// TR = (1-l1)*l2*time_attn + l1*rel_attn, fragment-packed:
// TRf[b][qt][w4][t16][lane64][4f], PMf[b][qt][w4][lr16][8 words]
__global__ __launch_bounds__(256) void tr_kernel(const float* __restrict__ rel,
                                                 const float* __restrict__ ts,
                                                 const void* __restrict__ maskp,
                                                 const int* __restrict__ msflag,
                                                 const float* __restrict__ l1p,
                                                 const float* __restrict__ l2p,
                                                 float* __restrict__ TRf,
                                                 uint32_t* __restrict__ PMf) {
    __shared__ float s_tm[4], s_rm[4], s_ts[4], s_rs[4];
    __shared__ unsigned char s_nib[256];
    int row = blockIdx.x;               // b*S + q
    int t = threadIdx.x, w = t >> 6, l = t & 63;
    int ms = *msflag;
    size_t base = (size_t)row * NS;
    float4 r4 = ((const float4*)(rel + base))[t];
    float4 t4 = ((const float4*)(ts + base))[t];
    float rr[4], tt[4];
    *(float4*)rr = r4; *(float4*)tt = t4;
    float tv[4], rv[4];
    unsigned nib = 0;
    float tmx = -3.0e38f, rmx = -3.0e38f;
    #pragma unroll
    for (int j = 0; j < 4; j++) {
        bool m = mask_at(maskp, base + t * 4 + j, ms);
        nib |= (m ? 1u : 0u) << j;
        tv[j] = m ? -100000.0f : __expf(-fabsf(tt[j]));
        float rm_ = m ? rr[j] : 0.0f;
        rv[j] = (rm_ == 0.0f) ? -100000.0f : rm_;
        tmx = fmaxf(tmx, tv[j]); rmx = fmaxf(rmx, rv[j]);
    }
    s_nib[t] = (unsigned char)nib;
    #pragma unroll
    for (int off = 1; off < 64; off <<= 1) {
        tmx = fmaxf(tmx, __shfl_xor(tmx, off));
        rmx = fmaxf(rmx, __shfl_xor(rmx, off));
    }
    if (l == 0) { s_tm[w] = tmx; s_rm[w] = rmx; }
    __syncthreads();
    tmx = fmaxf(fmaxf(s_tm[0], s_tm[1]), fmaxf(s_tm[2], s_tm[3]));
    rmx = fmaxf(fmaxf(s_rm[0], s_rm[1]), fmaxf(s_rm[2], s_rm[3]));
    float te[4], re[4], tsum = 0.f, rsum = 0.f;
    #pragma unroll
    for (int j = 0; j < 4; j++) {
        te[j] = __expf(tv[j] - tmx); tsum += te[j];
        re[j] = __expf(rv[j] - rmx); rsum += re[j];
    }
    #pragma unroll
    for (int off = 1; off < 64; off <<= 1) {
        tsum += __shfl_xor(tsum, off);
        rsum += __shfl_xor(rsum, off);
    }
    if (l == 0) { s_ts[w] = tsum; s_rs[w] = rsum; }
    __syncthreads();
    tsum = s_ts[0] + s_ts[1] + s_ts[2] + s_ts[3];
    rsum = s_rs[0] + s_rs[1] + s_rs[2] + s_rs[3];
    float l1 = *l1p, l2 = *l2p;
    float ti = ((1.0f - l1) * l2) / tsum;
    float ri = l1 / rsum;
    float4 o;
    o.x = te[0] * ti + re[0] * ri;
    o.y = te[1] * ti + re[1] * ri;
    o.z = te[2] * ti + re[2] * ri;
    o.w = te[3] * ti + re[3] * ri;
    int b = row >> 10, q = row & 1023;
    int qt = q >> 4, qr = q & 15;
    size_t slot = ((((size_t)(b * 64 + qt) * 4 + (t >> 6)) * 16 + ((t >> 2) & 15)) * 64
                   + (qr + 16 * (t & 3)));
    ((float4*)TRf)[slot] = o;
    if (t < 32) {
        uint32_t word = 0;
        #pragma unroll
        for (int i = 0; i < 8; i++)
            word |= ((uint32_t)s_nib[t * 8 + i]) << (i * 4);
        PMf[(((size_t)(b * 64 + qt) * 4 + (t >> 3)) * 16 + qr) * 8 + (t & 7)] = word;
    }
}

// Fused scores+softmax(no-max)+blend+PV. Per-wave self-contained PV via 16x16x16 MFMA
// (QK^T acc layout k=lg*4+r IS the K=16 input-frag layout -> zero redistribution).
// 2 barriers total: sum-reduce, out-reduce.
__global__ __launch_bounds__(256) void att_pv_kernel(const unsigned short* __restrict__ Qf,
                                                     const unsigned short* __restrict__ Kf,
                                                     const uint32_t* __restrict__ PMf,
                                                     const float* __restrict__ TRf,
                                                     const float* __restrict__ l1p,
                                                     const float* __restrict__ l2p,
                                                     const unsigned short* __restrict__ Vf,
                                                     float* __restrict__ probOut,
                                                     float* __restrict__ outp) {
    __shared__ float reds[4][16];
    __shared__ f32x4 pacc[4][4][64];   // 16 KB cross-wave out partials
    int bid = blockIdx.x;
    int swz = ((bid & 7) << 10) | (bid >> 3);   // XCD-aware, bijective (8192 = 8*1024)
    int qt = swz & 63;
    int h = (swz >> 6) & 15;
    int b = swz >> 10;
    int tid = threadIdx.x, w = tid >> 6, l = tid & 63, lr = l & 15, lg = l >> 4;
    int q0 = qt * 16;
    int k_base = w * 256;
    int q = q0 + lr;
    size_t bh = (size_t)(b * NH + h);

    const unsigned short* qf = Qf + (((bh * 64 + qt) * 2) * 64 + l) * 8;
    bf16x8 bq0 = *(const bf16x8*)(qf);
    bf16x8 bq1 = *(const bf16x8*)(qf + 64 * 8);

    const uint32_t* pmp = PMf + (((size_t)(b * 64 + qt) * 4 + w) * 16 + lr) * 8;
    uint32_t pm[8];
    *(uint4*)(pm) = *(const uint4*)(pmp);
    *(uint4*)(pm + 4) = *(const uint4*)(pmp + 4);

    f32x4 acc[16] = {};
    const unsigned short* kfb = Kf + (((bh * 64 + w * 16) * 2) * 64) * 8 + (size_t)l * 8;
    #pragma unroll
    for (int t = 0; t < 16; t++) {
        const unsigned short* kp = kfb + (size_t)t * 2 * 64 * 8;
        bf16x8 a0 = *(const bf16x8*)(kp);
        bf16x8 a1 = *(const bf16x8*)(kp + 64 * 8);
        acc[t] = mfma32(a0, bq0, acc[t]);
        acc[t] = mfma32(a1, bq1, acc[t]);
    }
    // mask + scale + exp (no max subtraction: |s/8| < ~5, f32-safe; masked -> 0)
    float sm = 0.f;
    #pragma unroll
    for (int t = 0; t < 16; t++) {
        uint32_t word = pm[t >> 1];
        int shift = (t & 1) * 16 + lg * 4;
        #pragma unroll
        for (int r = 0; r < 4; r++) {
            bool m = (word >> (shift + r)) & 1u;
            float e = m ? 0.0f : __expf(acc[t][r] * 0.125f);
            acc[t][r] = e;
            sm += e;
        }
    }
    sm += __shfl_xor(sm, 16);
    sm += __shfl_xor(sm, 32);
    if (l < 16) reds[w][l] = sm;
    __syncthreads();
    float total = reds[0][lr] + reds[1][lr] + reds[2][lr] + reds[3][lr];
    float l1 = *l1p, l2 = *l2p;
    float rinv = ((1.0f - l1) * (1.0f - l2)) / total;

    // fused blend + prob store + PV on this wave's k-slice
    float* po = probOut + bh * NS * NS + (size_t)q * NS + k_base;
    const float* trf = TRf + ((((size_t)(b * 64 + qt) * 4 + w) * 16) * 64 + l) * 4;
    const unsigned short* vf = Vf + ((((size_t)bh * 4 + w) * 8 * 4) * 64 + (size_t)l) * 8;
    f32x4 acc2[4] = {};
    #pragma unroll
    for (int tp = 0; tp < 8; tp++) {
        bf16x4 pfa, pfb;
        #pragma unroll
        for (int hf = 0; hf < 2; hf++) {
            int t = tp * 2 + hf;
            float4 tr4 = *(const float4*)(trf + t * 256);
            float4 o;
            o.x = acc[t][0] * rinv + tr4.x;
            o.y = acc[t][1] * rinv + tr4.y;
            o.z = acc[t][2] * rinv + tr4.z;
            o.w = acc[t][3] * rinv + tr4.w;
            *(float4*)(po + t * 16 + lg * 4) = o;
            bf16x4 pk;
            pk[0] = (short)f2bf(o.x); pk[1] = (short)f2bf(o.y);
            pk[2] = (short)f2bf(o.z); pk[3] = (short)f2bf(o.w);
            if (hf == 0) pfa = pk; else pfb = pk;
        }
        #pragma unroll
        for (int dt = 0; dt < 4; dt++) {
            bf16x8 vv = *(const bf16x8*)(vf + (size_t)(tp * 4 + dt) * 64 * 8);
            bf16x4 v0 = __builtin_shufflevector(vv, vv, 0, 1, 2, 3);
            bf16x4 v1 = __builtin_shufflevector(vv, vv, 4, 5, 6, 7);
            acc2[dt] = mfma16(v0, pfa, acc2[dt]);
            acc2[dt] = mfma16(v1, pfb, acc2[dt]);
        }
    }
    #pragma unroll
    for (int dt = 0; dt < 4; dt++) pacc[w][dt][l] = acc2[dt];
    __syncthreads();
    f32x4 s4 = pacc[0][w][l] + pacc[1][w][l] + pacc[2][w][l] + pacc[3][w][l];
    float4 ov;
    ov.x = s4[0]; ov.y = s4[1]; ov.z = s4[2]; ov.w = s4[3];
    *(float4*)(outp + ((size_t)b * NS + q0 + lr) * ND + h * NHD + w * 16 + lg * 4) = ov;
}

extern "C" void kernel_launch(void* const* d_in, const int* in_sizes, int n_in,
                              void* d_out, int out_size, void* d_ws, size_t ws_size,
                              hipStream_t stream) {
    const float* query = (const float*)d_in[0];
    const float* key   = (const float*)d_in[1];
    const float* value = (const float*)d_in[2];
    const float* rel   = (const float*)d_in[3];
    const float* ts    = (const float*)d_in[4];
    const void*  mask  = d_in[5];
    const float* l1p   = (const float*)d_in[6];
    const float* l2p   = (const float*)d_in[7];
    const float* Wq = (const float*)d_in[9];
    const float* bq = (const float*)d_in[10];
    const float* Wk = (const float*)d_in[11];
    const float* bk = (const float*)d_in[12];
    const float* Wv = (const float*)d_in[13];
    const float* bv = (const float*)d_in[14];

    char* ws = (char*)d_ws;
    const size_t SZ = (size_t)NB * NS * ND * 2;   // 16.78 MB
    unsigned short* Qf  = (unsigned short*)(ws);
    unsigned short* Kf  = (unsigned short*)(ws + SZ);
    unsigned short* Vf  = (unsigned short*)(ws + 2 * SZ);
    unsigned short* Afq = (unsigned short*)(ws + 3 * SZ);
    unsigned short* Afk = (unsigned short*)(ws + 4 * SZ);
    unsigned short* Afv = (unsigned short*)(ws + 5 * SZ);
    unsigned short* Wfq = (unsigned short*)(ws + 6 * SZ);
    unsigned short* Wfk = (unsigned short*)(ws + 6 * SZ + 2u * 1024 * 1024);
    unsigned short* Wfv = (unsigned short*)(ws + 6 * SZ + 4u * 1024 * 1024);
    int* msflag         = (int*)(ws + 6 * SZ + 6u * 1024 * 1024);
    uint32_t* PMf       = (uint32_t*)(ws + 6 * SZ + 8u * 1024 * 1024);  // 1 MB
    // TRf (33.55 MB = 2*SZ) reuses Afq+Afk — written only AFTER projections finish.
    float* TRf = (float*)(ws + 3 * SZ);

    detect_mask<<<1, 64, 0, stream>>>((const unsigned int*)mask, msflag);

    const int nX8 = NB * NS * ND / 8;
    const int nW8 = 1024 * 1024 / 8;
    cvt_frag<<<1024, 256, 0, stream>>>(query, Afq, nX8);
    cvt_frag<<<1024, 256, 0, stream>>>(key,   Afk, nX8);
    cvt_frag<<<1024, 256, 0, stream>>>(value, Afv, nX8);
    cvt_frag<<<256, 256, 0, stream>>>(Wq, Wfq, nW8);
    cvt_frag<<<256, 256, 0, stream>>>(Wk, Wfk, nW8);
    cvt_frag<<<256, 256, 0, stream>>>(Wv, Wfv, nW8);

    dim3 pg(64, 8);
    proj_gemm<<<pg, 256, 0, stream>>>(Afq, Wfq, bq, Qf, 0);
    proj_gemm<<<pg, 256, 0, stream>>>(Afk, Wfk, bk, Kf, 0);
    proj_gemm<<<pg, 256, 0, stream>>>(Afv, Wfv, bv, Vf, 1);

    tr_kernel<<<NB * NS, 256, 0, stream>>>(rel, ts, mask, msflag, l1p, l2p, TRf, PMf);

    float* outp = (float*)d_out;
    float* probOut = outp + (size_t)NB * NS * ND;
    att_pv_kernel<<<NB * NH * (NS / 16), 256, 0, stream>>>(Qf, Kf, PMf, TRf, l1p, l2p, Vf,
                                                           probOut, outp);
}

// Round 6
// 516.206 us; speedup vs baseline: 1.8275x; 1.1097x over previous
//
#include <hip/hip_runtime.h>
#include <stdint.h>

typedef short bf16x8 __attribute__((ext_vector_type(8)));
typedef short bf16x4 __attribute__((ext_vector_type(4)));
typedef float f32x4 __attribute__((ext_vector_type(4)));
typedef unsigned short u16x4 __attribute__((ext_vector_type(4)));
typedef unsigned short u16x8 __attribute__((ext_vector_type(8)));

constexpr int NB = 8, NS = 1024, ND = 1024, NH = 16, NHD = 64;

static __device__ __forceinline__ unsigned short f2bf(float f) {
    union { float f; uint32_t u; } v; v.f = f;
    uint32_t r = (v.u + 0x7fffu + ((v.u >> 16) & 1u)) >> 16;
    return (unsigned short)r;
}

static __device__ __forceinline__ f32x4 mfma32(bf16x8 a, bf16x8 b, f32x4 c) {
    return __builtin_amdgcn_mfma_f32_16x16x32_bf16(a, b, c, 0, 0, 0);
}

// K=16 bf16 MFMA: A/B frag = 4 bf16 (k = (l>>4)*4 + e), C/D = f32x4.
static __device__ __forceinline__ f32x4 mfma16(bf16x4 a, bf16x4 b, f32x4 c) {
#if __has_builtin(__builtin_amdgcn_mfma_f32_16x16x16bf16_1k)
    return __builtin_amdgcn_mfma_f32_16x16x16bf16_1k(a, b, c, 0, 0, 0);
#elif __has_builtin(__builtin_amdgcn_mfma_f32_16x16x16_bf16)
    return __builtin_amdgcn_mfma_f32_16x16x16_bf16(a, b, c, 0, 0, 0);
#else
    asm volatile("v_mfma_f32_16x16x16_bf16 %0, %1, %2, %0\n\ts_nop 7\n\ts_nop 7"
                 : "+v"(c) : "v"(a), "v"(b));
    return c;
#endif
}

static __device__ __forceinline__ bool mask_at(const void* m, size_t idx, int ms) {
    if (ms == 4) return ((const unsigned int*)m)[idx] != 0u;
    return ((const unsigned char*)m)[idx] != 0;
}

__global__ void detect_mask(const unsigned int* __restrict__ m, int* __restrict__ flag) {
    int l = threadIdx.x;
    bool bad = false;
    for (int i = l; i < 1024; i += 64) {
        unsigned int w = m[i];
        bad |= (w > 1u && w != 0x3f800000u);
    }
    bad = (bool)__any(bad);
    if (l == 0) *flag = bad ? 1 : 4;
}

// f32 [M][1024] -> fragment-packed bf16 [M/16][32 kt][64 lane][8]
__global__ __launch_bounds__(256) void cvt_frag(const float* __restrict__ in,
                                                unsigned short* __restrict__ out, int n8) {
    int stride = gridDim.x * blockDim.x;
    for (int idx = blockIdx.x * blockDim.x + threadIdx.x; idx < n8; idx += stride) {
        const float4* p = (const float4*)in + 2 * (size_t)idx;
        float4 a = p[0], b = p[1];
        u16x8 o;
        o[0] = f2bf(a.x); o[1] = f2bf(a.y); o[2] = f2bf(a.z); o[3] = f2bf(a.w);
        o[4] = f2bf(b.x); o[5] = f2bf(b.y); o[6] = f2bf(b.z); o[7] = f2bf(b.w);
        int m = idx >> 7, c8 = idx & 127;
        int kt = c8 >> 2, sub = c8 & 3;
        int lane = (m & 15) + 16 * sub;
        size_t slot = ((size_t)(m >> 4) * 32 + kt) * 64 + lane;
        *(u16x8*)(out + slot * 8) = o;
    }
}

// C(M x N) = A(MxK)*W(NxK)^T + bias, inputs fragment-packed [*/16][32][64][8].
// mode 0: QKf[b][h][s/16][d32][64][8]           (K=32 frag layout for QK^T)
// mode 1: Vf [b][h][tp32][dt4][64][4+4]         (K=16 frag pairs for PV; k-dim = s)
__global__ __launch_bounds__(256) void proj_gemm(const unsigned short* __restrict__ Af,
                                                 const unsigned short* __restrict__ Wf,
                                                 const float* __restrict__ bias,
                                                 unsigned short* __restrict__ C, int mode) {
    int l = threadIdx.x & 63, w = threadIdx.x >> 6;
    int lr = l & 15, lg = l >> 4;
    int m_base = blockIdx.x * 128 + (w >> 1) * 64;
    int n_base = blockIdx.y * 128 + (w & 1) * 64;
    int mtg0 = m_base >> 4, ntg0 = n_base >> 4;
    f32x4 acc[4][4] = {};
    for (int kt = 0; kt < 32; kt++) {
        bf16x8 af[4], bfr[4];
        #pragma unroll
        for (int mt = 0; mt < 4; mt++)
            af[mt] = *(const bf16x8*)(Af + (((size_t)(mtg0 + mt) * 32 + kt) * 64 + l) * 8);
        #pragma unroll
        for (int nt = 0; nt < 4; nt++)
            bfr[nt] = *(const bf16x8*)(Wf + (((size_t)(ntg0 + nt) * 32 + kt) * 64 + l) * 8);
        #pragma unroll
        for (int mt = 0; mt < 4; mt++) {
            #pragma unroll
            for (int nt = 0; nt < 4; nt++)
                acc[mt][nt] = mfma32(af[mt], bfr[nt], acc[mt][nt]);
        }
    }
    #pragma unroll
    for (int mt = 0; mt < 4; mt++) {
        #pragma unroll
        for (int nt = 0; nt < 4; nt++) {
            int col = n_base + nt * 16 + lr;          // output feature n
            int row0 = m_base + mt * 16 + lg * 4;     // flattened (b*S + s)
            float bv = bias[col];
            int b = row0 >> 10;
            int h = col >> 6;
            if (mode == 0) {
                int st = (row0 & 1023) >> 4;
                int d32 = (col & 63) >> 5;
                int sub = (col & 31) >> 3;
                int e = col & 7;
                size_t base = ((((size_t)(b * NH + h) * 64 + st) * 2 + d32) * 64) * 8;
                #pragma unroll
                for (int r = 0; r < 4; r++) {
                    int lane = lg * 4 + r + 16 * sub;
                    C[base + (size_t)lane * 8 + e] = f2bf(acc[mt][nt][r] + bv);
                }
            } else {
                int s0 = row0 & 1023;        // lg*4-aligned
                int tg = s0 >> 4;            // global 16-k tile index (0..63)
                int tp = tg >> 1, half = tg & 1;
                int dd = col & 63;
                int dt = dd >> 4;
                int lane = (dd & 15) + 16 * lg;
                u16x4 pk;
                #pragma unroll
                for (int r = 0; r < 4; r++) pk[r] = f2bf(acc[mt][nt][r] + bv);
                size_t addr = ((((size_t)(b * NH + h) * 32 + tp) * 4 + dt) * 64 + lane) * 8
                              + half * 4;
                *(u16x4*)(C + addr) = pk;
            }
        }
    }
}

// TR = (1-l1)*l2*time_attn + l1*rel_attn, fragment-packed:
// TRf[b][qt][t64][lane64][4f]  (float4 t covers k=t*16+lg*4, lane=(q&15)+16*lg)
// PMf[b][qt][qr16][32 words]   full-row packed mask per q-row
__global__ __launch_bounds__(256) void tr_kernel(const float* __restrict__ rel,
                                                 const float* __restrict__ ts,
                                                 const void* __restrict__ maskp,
                                                 const int* __restrict__ msflag,
                                                 const float* __restrict__ l1p,
                                                 const float* __restrict__ l2p,
                                                 float* __restrict__ TRf,
                                                 uint32_t* __restrict__ PMf) {
    __shared__ float s_tm[4], s_rm[4], s_ts[4], s_rs[4];
    __shared__ unsigned char s_nib[256];
    int row = blockIdx.x;               // b*S + q
    int t = threadIdx.x, w = t >> 6, l = t & 63;
    int ms = *msflag;
    size_t base = (size_t)row * NS;
    float4 r4 = ((const float4*)(rel + base))[t];
    float4 t4 = ((const float4*)(ts + base))[t];
    float rr[4], tt[4];
    *(float4*)rr = r4; *(float4*)tt = t4;
    float tv[4], rv[4];
    unsigned nib = 0;
    float tmx = -3.0e38f, rmx = -3.0e38f;
    #pragma unroll
    for (int j = 0; j < 4; j++) {
        bool m = mask_at(maskp, base + t * 4 + j, ms);
        nib |= (m ? 1u : 0u) << j;
        tv[j] = m ? -100000.0f : __expf(-fabsf(tt[j]));
        float rm_ = m ? rr[j] : 0.0f;
        rv[j] = (rm_ == 0.0f) ? -100000.0f : rm_;
        tmx = fmaxf(tmx, tv[j]); rmx = fmaxf(rmx, rv[j]);
    }
    s_nib[t] = (unsigned char)nib;
    #pragma unroll
    for (int off = 1; off < 64; off <<= 1) {
        tmx = fmaxf(tmx, __shfl_xor(tmx, off));
        rmx = fmaxf(rmx, __shfl_xor(rmx, off));
    }
    if (l == 0) { s_tm[w] = tmx; s_rm[w] = rmx; }
    __syncthreads();
    tmx = fmaxf(fmaxf(s_tm[0], s_tm[1]), fmaxf(s_tm[2], s_tm[3]));
    rmx = fmaxf(fmaxf(s_rm[0], s_rm[1]), fmaxf(s_rm[2], s_rm[3]));
    float te[4], re[4], tsum = 0.f, rsum = 0.f;
    #pragma unroll
    for (int j = 0; j < 4; j++) {
        te[j] = __expf(tv[j] - tmx); tsum += te[j];
        re[j] = __expf(rv[j] - rmx); rsum += re[j];
    }
    #pragma unroll
    for (int off = 1; off < 64; off <<= 1) {
        tsum += __shfl_xor(tsum, off);
        rsum += __shfl_xor(rsum, off);
    }
    if (l == 0) { s_ts[w] = tsum; s_rs[w] = rsum; }
    __syncthreads();
    tsum = s_ts[0] + s_ts[1] + s_ts[2] + s_ts[3];
    rsum = s_rs[0] + s_rs[1] + s_rs[2] + s_rs[3];
    float l1 = *l1p, l2 = *l2p;
    float ti = ((1.0f - l1) * l2) / tsum;
    float ri = l1 / rsum;
    float4 o;
    o.x = te[0] * ti + re[0] * ri;
    o.y = te[1] * ti + re[1] * ri;
    o.z = te[2] * ti + re[2] * ri;
    o.w = te[3] * ti + re[3] * ri;
    int b = row >> 10, q = row & 1023;
    int qt = q >> 4, qr = q & 15;
    // float4 covers k = t*4..t*4+3 -> kt16 = t>>2, lg = t&3; lane = qr + 16*(t&3)
    size_t slot = ((size_t)(b * 64 + qt) * 64 + (t >> 2)) * 64 + (qr + 16 * (t & 3));
    ((float4*)TRf)[slot] = o;
    if (t < 32) {
        uint32_t word = 0;
        #pragma unroll
        for (int i = 0; i < 8; i++)
            word |= ((uint32_t)s_nib[t * 8 + i]) << (i * 4);
        PMf[((size_t)(b * 64 + qt) * 16 + qr) * 32 + t] = word;
    }
}

// Fused scores+softmax(no-max)+blend+PV, ONE WAVE per block, zero barriers, zero LDS.
// Pass 1: QK^T + exp -> row-sum (in-register + 2 shfl).
// Pass 2: recompute QK^T + exp, blend TR, store prob f32, pack bf16 -> PV mfma16.
__global__ __launch_bounds__(64, 4) void att_pv_kernel(const unsigned short* __restrict__ Qf,
                                                       const unsigned short* __restrict__ Kf,
                                                       const uint32_t* __restrict__ PMf,
                                                       const float* __restrict__ TRf,
                                                       const float* __restrict__ l1p,
                                                       const float* __restrict__ l2p,
                                                       const unsigned short* __restrict__ Vf,
                                                       float* __restrict__ probOut,
                                                       float* __restrict__ outp) {
    int bid = blockIdx.x;
    int swz = ((bid & 7) << 10) | (bid >> 3);   // XCD-aware, bijective (8192 = 8*1024)
    int qt = swz & 63;
    int h = (swz >> 6) & 15;
    int b = swz >> 10;
    int l = threadIdx.x, lr = l & 15, lg = l >> 4;
    int q0 = qt * 16;
    int q = q0 + lr;                   // this lane's q-row
    size_t bh = (size_t)(b * NH + h);

    const unsigned short* qf = Qf + (((bh * 64 + qt) * 2) * 64 + l) * 8;
    bf16x8 bq0 = *(const bf16x8*)(qf);
    bf16x8 bq1 = *(const bf16x8*)(qf + 64 * 8);

    const unsigned short* kfb = Kf + ((bh * 64 * 2) * 64) * 8 + (size_t)l * 8;
    const uint32_t* pmrow = PMf + ((size_t)(b * 64 + qt) * 16 + lr) * 32;

    // ---- pass 1: row sums ----
    float sm = 0.f;
    for (int t8 = 0; t8 < 8; t8++) {
        uint32_t pmw[4];
        *(uint4*)pmw = *(const uint4*)(pmrow + t8 * 4);
        #pragma unroll
        for (int tt = 0; tt < 8; tt++) {
            int t = t8 * 8 + tt;
            const unsigned short* kp = kfb + (size_t)t * 1024;
            bf16x8 a0 = *(const bf16x8*)kp;
            bf16x8 a1 = *(const bf16x8*)(kp + 512);
            f32x4 acc = {};
            acc = mfma32(a0, bq0, acc);
            acc = mfma32(a1, bq1, acc);
            uint32_t word = pmw[tt >> 1];
            int shift = (tt & 1) * 16 + lg * 4;
            #pragma unroll
            for (int r = 0; r < 4; r++) {
                bool m = (word >> (shift + r)) & 1u;
                sm += m ? 0.0f : __expf(acc[r] * 0.125f);
            }
        }
    }
    sm += __shfl_xor(sm, 16);
    sm += __shfl_xor(sm, 32);
    float l1 = *l1p, l2 = *l2p;
    float rinv = ((1.0f - l1) * (1.0f - l2)) / sm;

    // ---- pass 2: blend + prob store + PV ----
    float* po = probOut + bh * NS * NS + (size_t)q * NS;
    const float4* trf = (const float4*)TRf + ((size_t)(b * 64 + qt) * 64) * 64 + l;
    const unsigned short* vf = Vf + (bh * 32 * 4 * 64) * 8 + (size_t)l * 8;
    f32x4 acc2[4] = {};
    for (int tq = 0; tq < 8; tq++) {
        uint32_t pmw[4];
        *(uint4*)pmw = *(const uint4*)(pmrow + tq * 4);
        #pragma unroll
        for (int tpi = 0; tpi < 4; tpi++) {
            int tp = tq * 4 + tpi;
            bf16x4 pf0, pf1;
            #pragma unroll
            for (int hf = 0; hf < 2; hf++) {
                int t = tp * 2 + hf;
                const unsigned short* kp = kfb + (size_t)t * 1024;
                bf16x8 a0 = *(const bf16x8*)kp;
                bf16x8 a1 = *(const bf16x8*)(kp + 512);
                f32x4 acc = {};
                acc = mfma32(a0, bq0, acc);
                acc = mfma32(a1, bq1, acc);
                uint32_t word = pmw[tpi];
                int shift = hf * 16 + lg * 4;
                float4 tr4 = ((const float4*)trf)[(size_t)t * 64];
                float4 o;
                float e0 = ((word >> (shift + 0)) & 1u) ? 0.f : __expf(acc[0] * 0.125f);
                float e1 = ((word >> (shift + 1)) & 1u) ? 0.f : __expf(acc[1] * 0.125f);
                float e2 = ((word >> (shift + 2)) & 1u) ? 0.f : __expf(acc[2] * 0.125f);
                float e3 = ((word >> (shift + 3)) & 1u) ? 0.f : __expf(acc[3] * 0.125f);
                o.x = e0 * rinv + tr4.x;
                o.y = e1 * rinv + tr4.y;
                o.z = e2 * rinv + tr4.z;
                o.w = e3 * rinv + tr4.w;
                *(float4*)(po + t * 16 + lg * 4) = o;
                bf16x4 pk;
                pk[0] = (short)f2bf(o.x); pk[1] = (short)f2bf(o.y);
                pk[2] = (short)f2bf(o.z); pk[3] = (short)f2bf(o.w);
                if (hf == 0) pf0 = pk; else pf1 = pk;
            }
            #pragma unroll
            for (int dt = 0; dt < 4; dt++) {
                bf16x8 vv = *(const bf16x8*)(vf + (size_t)(tp * 4 + dt) * 512);
                bf16x4 v0 = __builtin_shufflevector(vv, vv, 0, 1, 2, 3);
                bf16x4 v1 = __builtin_shufflevector(vv, vv, 4, 5, 6, 7);
                acc2[dt] = mfma16(v0, pf0, acc2[dt]);
                acc2[dt] = mfma16(v1, pf1, acc2[dt]);
            }
        }
    }
    // out: d = dt*16 + lg*4 + r, row q
    float* orow = outp + ((size_t)b * NS + q) * ND + h * NHD + lg * 4;
    #pragma unroll
    for (int dt = 0; dt < 4; dt++) {
        float4 ov;
        ov.x = acc2[dt][0]; ov.y = acc2[dt][1]; ov.z = acc2[dt][2]; ov.w = acc2[dt][3];
        *(float4*)(orow + dt * 16) = ov;
    }
}

extern "C" void kernel_launch(void* const* d_in, const int* in_sizes, int n_in,
                              void* d_out, int out_size, void* d_ws, size_t ws_size,
                              hipStream_t stream) {
    const float* query = (const float*)d_in[0];
    const float* key   = (const float*)d_in[1];
    const float* value = (const float*)d_in[2];
    const float* rel   = (const float*)d_in[3];
    const float* ts    = (const float*)d_in[4];
    const void*  mask  = d_in[5];
    const float* l1p   = (const float*)d_in[6];
    const float* l2p   = (const float*)d_in[7];
    const float* Wq = (const float*)d_in[9];
    const float* bq = (const float*)d_in[10];
    const float* Wk = (const float*)d_in[11];
    const float* bk = (const float*)d_in[12];
    const float* Wv = (const float*)d_in[13];
    const float* bv = (const float*)d_in[14];

    char* ws = (char*)d_ws;
    const size_t SZ = (size_t)NB * NS * ND * 2;   // 16.78 MB
    unsigned short* Qf  = (unsigned short*)(ws);
    unsigned short* Kf  = (unsigned short*)(ws + SZ);
    unsigned short* Vf  = (unsigned short*)(ws + 2 * SZ);
    unsigned short* Afq = (unsigned short*)(ws + 3 * SZ);
    unsigned short* Afk = (unsigned short*)(ws + 4 * SZ);
    unsigned short* Afv = (unsigned short*)(ws + 5 * SZ);
    unsigned short* Wfq = (unsigned short*)(ws + 6 * SZ);
    unsigned short* Wfk = (unsigned short*)(ws + 6 * SZ + 2u * 1024 * 1024);
    unsigned short* Wfv = (unsigned short*)(ws + 6 * SZ + 4u * 1024 * 1024);
    int* msflag         = (int*)(ws + 6 * SZ + 6u * 1024 * 1024);
    uint32_t* PMf       = (uint32_t*)(ws + 6 * SZ + 8u * 1024 * 1024);  // 1 MB
    // TRf (33.55 MB = 2*SZ) reuses Afq+Afk — written only AFTER projections finish.
    float* TRf = (float*)(ws + 3 * SZ);

    detect_mask<<<1, 64, 0, stream>>>((const unsigned int*)mask, msflag);

    const int nX8 = NB * NS * ND / 8;
    const int nW8 = 1024 * 1024 / 8;
    cvt_frag<<<1024, 256, 0, stream>>>(query, Afq, nX8);
    cvt_frag<<<1024, 256, 0, stream>>>(key,   Afk, nX8);
    cvt_frag<<<1024, 256, 0, stream>>>(value, Afv, nX8);
    cvt_frag<<<256, 256, 0, stream>>>(Wq, Wfq, nW8);
    cvt_frag<<<256, 256, 0, stream>>>(Wk, Wfk, nW8);
    cvt_frag<<<256, 256, 0, stream>>>(Wv, Wfv, nW8);

    dim3 pg(64, 8);
    proj_gemm<<<pg, 256, 0, stream>>>(Afq, Wfq, bq, Qf, 0);
    proj_gemm<<<pg, 256, 0, stream>>>(Afk, Wfk, bk, Kf, 0);
    proj_gemm<<<pg, 256, 0, stream>>>(Afv, Wfv, bv, Vf, 1);

    tr_kernel<<<NB * NS, 256, 0, stream>>>(rel, ts, mask, msflag, l1p, l2p, TRf, PMf);

    float* outp = (float*)d_out;
    float* probOut = outp + (size_t)NB * NS * ND;
    att_pv_kernel<<<NB * NH * (NS / 16), 64, 0, stream>>>(Qf, Kf, PMf, TRf, l1p, l2p, Vf,
                                                          probOut, outp);
}